// Round 7
// baseline (924.210 us; speedup 1.0000x reference)
//
#include <hip/hip_runtime.h>

#define D 256
#define BM 128
#define BN2 256
#define BK 64
#define SCAN_NB 64
#define SCAN_T (SCAN_NB * 256)

typedef __attribute__((ext_vector_type(8))) short bf16x8;
typedef __attribute__((ext_vector_type(4))) float f32x4;
typedef __attribute__((ext_vector_type(4))) unsigned int u32x4;

union frag_cvt { u32x4 u; bf16x8 h; };

__device__ __forceinline__ unsigned short bf16_rn(float f) {
    const unsigned int u = __float_as_uint(f);
    return (unsigned short)((u + 0x7FFFu + ((u >> 16) & 1u)) >> 16);
}
__device__ __forceinline__ float bf16_to_f32(unsigned short s) {
    return __uint_as_float(((unsigned int)s) << 16);
}

// ---------------- fp32 -> bf16 (RN) ----------------
__global__ void f32_to_bf16_rn_kernel(const float* __restrict__ s,
                                      unsigned short* __restrict__ d, int n)
{
    const int i = blockIdx.x * 256 + threadIdx.x;
    if (i < n) d[i] = bf16_rn(s[i]);
}

// ---------------- x -> (hi trunc, lo = exact remainder) bf16 planes ----------------
__global__ __launch_bounds__(256) void split_x_kernel(
    const float* __restrict__ x, unsigned short* __restrict__ hi,
    unsigned short* __restrict__ lo, size_t n4)
{
    const size_t i = (size_t)blockIdx.x * 256 + threadIdx.x;
    if (i >= n4) return;
    const float4 v = *(const float4*)(x + i * 4);
    ushort4 h4, l4;
    {
        const unsigned int u = __float_as_uint(v.x);
        h4.x = (unsigned short)(u >> 16);
        l4.x = (unsigned short)(__float_as_uint(v.x - __uint_as_float(u & 0xFFFF0000u)) >> 16);
    }
    {
        const unsigned int u = __float_as_uint(v.y);
        h4.y = (unsigned short)(u >> 16);
        l4.y = (unsigned short)(__float_as_uint(v.y - __uint_as_float(u & 0xFFFF0000u)) >> 16);
    }
    {
        const unsigned int u = __float_as_uint(v.z);
        h4.z = (unsigned short)(u >> 16);
        l4.z = (unsigned short)(__float_as_uint(v.z - __uint_as_float(u & 0xFFFF0000u)) >> 16);
    }
    {
        const unsigned int u = __float_as_uint(v.w);
        h4.w = (unsigned short)(u >> 16);
        l4.w = (unsigned short)(__float_as_uint(v.w - __uint_as_float(u & 0xFFFF0000u)) >> 16);
    }
    *(ushort4*)(hi + i * 4) = h4;
    *(ushort4*)(lo + i * 4) = l4;
}

// ---------------- W_eff = W + lora_B . lora_A  -> bf16 ----------------
__global__ __launch_bounds__(256) void lora_fold_kernel(
    const float* __restrict__ W, const float* __restrict__ lA,
    const float* __restrict__ lB, unsigned short* __restrict__ out)
{
    const int t = blockIdx.z, o = blockIdx.x, d = threadIdx.x;
    float acc = W[((size_t)t * D + o) * D + d];
    const float* Br = lB + ((size_t)t * D + o) * 16;
    const float* At = lA + (size_t)t * 16 * D;
    #pragma unroll
    for (int r = 0; r < 16; ++r) acc = fmaf(Br[r], At[r * D + d], acc);
    out[((size_t)t * D + o) * D + d] = bf16_rn(acc);
}

// ---------------- P[t,p,:] = sum_o X[t,p,o] * Y[t,o,:] ----------------
__global__ __launch_bounds__(256) void mm_nn_kernel(
    const float* __restrict__ X, const float* __restrict__ Y,
    float* __restrict__ Pf, unsigned short* __restrict__ Pb)
{
    const int t = blockIdx.z, p = blockIdx.x, d = threadIdx.x;
    const float* Xr = X + ((size_t)t * D + p) * D;
    const float* Yt = Y + (size_t)t * D * D;
    float acc = 0.f;
    for (int o = 0; o < D; ++o) acc = fmaf(Xr[o], Yt[(size_t)o * D + d], acc);
    if (Pf) Pf[((size_t)t * D + p) * D + d] = acc;
    if (Pb) Pb[((size_t)t * D + p) * D + d] = bf16_rn(acc);
}

// ---------------- out[t,p] = add[t,p] + sum_o M[t,p,o] * v[t,o] ----------------
__global__ __launch_bounds__(256) void mv_kernel(
    const float* __restrict__ M, const float* __restrict__ v,
    const float* __restrict__ add, float* __restrict__ out)
{
    const int t = blockIdx.z, p = threadIdx.x;
    const float* Mr = M + ((size_t)t * D + p) * D;
    const float* vr = v + (size_t)t * D;
    float acc = add[(size_t)t * D + p];
    for (int o = 0; o < D; ++o) acc = fmaf(Mr[o], vr[o], acc);
    out[(size_t)t * D + p] = acc;
}

// ======== fused GEMM (2-operand) + bias + residual + LayerNorm epilogue ========
// C_pre = A.W1^T + A2[swap].W2^T + bias (+ res); out = LN(C_pre)*g + b
// Tile BM=128 x BN2=256 (full row), 4 waves 2x2 (per wave 64 rows x 128 cols).
__global__ __launch_bounds__(256) void gemm_ln_kernel(
    const unsigned short* __restrict__ A, const unsigned short* __restrict__ W1,
    const unsigned short* __restrict__ A2, const unsigned short* __restrict__ W2,
    const float* __restrict__ bias, const float* __restrict__ res,
    const float* __restrict__ g, const float* __restrict__ b,
    unsigned short* __restrict__ out_bf, float* __restrict__ out_f,
    int M, int swap2)
{
    const int t   = blockIdx.z;
    const int m0  = blockIdx.x * BM;
    const int tid = threadIdx.x;
    const int lane = tid & 63;
    const int wid  = tid >> 6;
    const int wr = (wid >> 1) * 64;     // local row base of wave
    const int wc = (wid & 1) * 128;     // local col base of wave
    const int rgrp = lane >> 4;
    const int cidx = lane & 15;

    __shared__ __align__(16) unsigned short As[BM * BK];   // 16 KB
    __shared__ __align__(16) unsigned short Bs[BN2 * BK];  // 32 KB
    char* AsB = (char*)As;
    char* BsB = (char*)Bs;

    f32x4 acc[4][8];
    #pragma unroll
    for (int m = 0; m < 4; ++m)
        #pragma unroll
        for (int n = 0; n < 8; ++n)
            acc[m][n] = (f32x4){0.f, 0.f, 0.f, 0.f};

    #pragma unroll 1
    for (int pass = 0; pass < 2; ++pass) {
        const unsigned short* Ap;
        const unsigned short* Wp;
        if (pass == 0) {
            Ap = A + (size_t)t * M * D;
            Wp = W1 + (size_t)t * D * D;
        } else {
            const int t2 = swap2 ? (1 - t) : t;
            Ap = A2 + (size_t)t2 * M * D;
            Wp = W2 + (size_t)t * D * D;
        }
        for (int kt = 0; kt < D; kt += BK) {
            // stage A: 128 rows x 64 k (4 rounds)
            #pragma unroll
            for (int it = 0; it < 4; ++it) {
                const int gidx = tid + it * 256;
                const int row = gidx >> 3;
                const int kg  = gidx & 7;
                const int ar  = m0 + row;
                u32x4 av = (u32x4){0u, 0u, 0u, 0u};
                if (ar < M) av = *(const u32x4*)(Ap + (size_t)ar * D + kt + kg * 8);
                const int sw = ((row * BK + kg * 8) * 2) ^ ((row & 7) << 4);
                *(u32x4*)(AsB + sw) = av;
            }
            // stage B: 256 rows x 64 k (8 rounds)
            #pragma unroll
            for (int it = 0; it < 8; ++it) {
                const int gidx = tid + it * 256;
                const int row = gidx >> 3;
                const int kg  = gidx & 7;
                const u32x4 wv = *(const u32x4*)(Wp + (size_t)row * D + kt + kg * 8);
                const int sw = ((row * BK + kg * 8) * 2) ^ ((row & 7) << 4);
                *(u32x4*)(BsB + sw) = wv;
            }
            __syncthreads();
            #pragma unroll
            for (int ks = 0; ks < 2; ++ks) {
                const int kb = ks * 64 + rgrp * 16;
                bf16x8 af[4], bfr[8];
                #pragma unroll
                for (int m = 0; m < 4; ++m) {
                    const int row = wr + m * 16 + cidx;
                    const int sw  = (row * 128 + kb) ^ ((row & 7) << 4);
                    frag_cvt c; c.u = *(u32x4*)(AsB + sw); af[m] = c.h;
                }
                #pragma unroll
                for (int n = 0; n < 8; ++n) {
                    const int row = wc + n * 16 + cidx;
                    const int sw  = (row * 128 + kb) ^ ((row & 7) << 4);
                    frag_cvt c; c.u = *(u32x4*)(BsB + sw); bfr[n] = c.h;
                }
                #pragma unroll
                for (int m = 0; m < 4; ++m)
                    #pragma unroll
                    for (int n = 0; n < 8; ++n)
                        acc[m][n] = __builtin_amdgcn_mfma_f32_16x16x32_bf16(af[m], bfr[n], acc[m][n], 0, 0, 0);
            }
            __syncthreads();
        }
    }

    // ---------------- epilogue: bias + residual + LN ----------------
    float* red  = (float*)As;          // [128][2] row sums
    float* red2 = red + 256;           // [128][2] row sq-sums

    // bias
    #pragma unroll
    for (int n = 0; n < 8; ++n) {
        const float bc = bias[t * D + wc + n * 16 + cidx];
        #pragma unroll
        for (int m = 0; m < 4; ++m)
            #pragma unroll
            for (int i = 0; i < 4; ++i)
                acc[m][n][i] += bc;
    }
    // residual
    if (res) {
        #pragma unroll
        for (int m = 0; m < 4; ++m)
            #pragma unroll
            for (int i = 0; i < 4; ++i) {
                const int row = m0 + wr + m * 16 + rgrp * 4 + i;
                if (row < M) {
                    const float* rr = res + ((size_t)t * M + row) * D + wc + cidx;
                    #pragma unroll
                    for (int n = 0; n < 8; ++n)
                        acc[m][n][i] += rr[n * 16];
                }
            }
    }
    // mean
    float mu[4][4];
    #pragma unroll
    for (int m = 0; m < 4; ++m)
        #pragma unroll
        for (int i = 0; i < 4; ++i) {
            float s = 0.f;
            #pragma unroll
            for (int n = 0; n < 8; ++n) s += acc[m][n][i];
            s += __shfl_xor(s, 1); s += __shfl_xor(s, 2);
            s += __shfl_xor(s, 4); s += __shfl_xor(s, 8);
            if (cidx == 0) red[(wr + m * 16 + rgrp * 4 + i) * 2 + (wid & 1)] = s;
            mu[m][i] = s;   // placeholder
        }
    __syncthreads();
    #pragma unroll
    for (int m = 0; m < 4; ++m)
        #pragma unroll
        for (int i = 0; i < 4; ++i) {
            const int lr = wr + m * 16 + rgrp * 4 + i;
            mu[m][i] = (red[lr * 2] + red[lr * 2 + 1]) * (1.0f / 256.0f);
        }
    // variance
    float rstd[4][4];
    #pragma unroll
    for (int m = 0; m < 4; ++m)
        #pragma unroll
        for (int i = 0; i < 4; ++i) {
            float q = 0.f;
            #pragma unroll
            for (int n = 0; n < 8; ++n) {
                const float d0 = acc[m][n][i] - mu[m][i];
                q += d0 * d0;
            }
            q += __shfl_xor(q, 1); q += __shfl_xor(q, 2);
            q += __shfl_xor(q, 4); q += __shfl_xor(q, 8);
            if (cidx == 0) red2[(wr + m * 16 + rgrp * 4 + i) * 2 + (wid & 1)] = q;
        }
    __syncthreads();
    #pragma unroll
    for (int m = 0; m < 4; ++m)
        #pragma unroll
        for (int i = 0; i < 4; ++i) {
            const int lr = wr + m * 16 + rgrp * 4 + i;
            rstd[m][i] = rsqrtf((red2[lr * 2] + red2[lr * 2 + 1]) * (1.0f / 256.0f) + 1e-5f);
        }
    // normalize + store
    #pragma unroll
    for (int n = 0; n < 8; ++n) {
        const int col = wc + n * 16 + cidx;
        const float gv = g[t * D + col];
        const float bv = b[t * D + col];
        #pragma unroll
        for (int m = 0; m < 4; ++m)
            #pragma unroll
            for (int i = 0; i < 4; ++i) {
                const int row = m0 + wr + m * 16 + rgrp * 4 + i;
                if (row < M) {
                    const float o = (acc[m][n][i] - mu[m][i]) * rstd[m][i] * gv + bv;
                    const size_t idx = ((size_t)t * M + row) * D + col;
                    if (out_bf) out_bf[idx] = bf16_rn(o);
                    if (out_f)  out_f[idx]  = o;
                }
            }
    }
}

// ---------------- CSR build ----------------
__global__ void count_kernel(const int* __restrict__ e_dst, int* __restrict__ cnt,
                             int E2, int N, int E)
{
    const int i = blockIdx.x * 256 + threadIdx.x;
    if (i >= E2) return;
    const int t = i / E;
    atomicAdd(&cnt[(size_t)t * N + e_dst[i]], 1);
}

__global__ __launch_bounds__(256) void scan1_kernel(const int* __restrict__ cnt,
                                                    int* __restrict__ texcl,
                                                    int* __restrict__ bsum, int n, int c)
{
    __shared__ int ts[256];
    const int tid = threadIdx.x;
    const int gt  = blockIdx.x * 256 + tid;
    const int b   = gt * c;
    const int e   = min(b + c, n);
    int s = 0;
    for (int i = b; i < e; ++i) s += cnt[i];
    ts[tid] = s;
    __syncthreads();
    #pragma unroll
    for (int off = 1; off < 256; off <<= 1) {
        const int v = (tid >= off) ? ts[tid - off] : 0;
        __syncthreads();
        ts[tid] += v;
        __syncthreads();
    }
    texcl[gt] = ts[tid] - s;
    if (tid == 255) bsum[blockIdx.x] = ts[255];
}

__global__ __launch_bounds__(64) void scan2_kernel(int* __restrict__ bsum,
                                                   int* __restrict__ bbase,
                                                   int* __restrict__ offs, int n, int nb)
{
    const int lane = threadIdx.x;
    int v = (lane < nb) ? bsum[lane] : 0;
    int s = v;
    #pragma unroll
    for (int off = 1; off < 64; off <<= 1) {
        const int u = __shfl_up(s, off);
        if (lane >= off) s += u;
    }
    if (lane < nb) bbase[lane] = s - v;
    if (lane == 63) offs[n] = s;
}

__global__ __launch_bounds__(256) void scan3_kernel(const int* __restrict__ cnt,
                                                    const int* __restrict__ texcl,
                                                    const int* __restrict__ bbase,
                                                    int* __restrict__ offs, int n, int c)
{
    const int tid = threadIdx.x;
    const int gt  = blockIdx.x * 256 + tid;
    const int b   = gt * c;
    const int e   = min(b + c, n);
    int base = bbase[blockIdx.x] + texcl[gt];
    for (int i = b; i < e; ++i) { offs[i] = base; base += cnt[i]; }
}

__global__ void fill_kernel(const int* __restrict__ e_src, const int* __restrict__ e_dst,
                            const int* __restrict__ offs, int* __restrict__ cur,
                            int* __restrict__ sorted, int E2, int N, int E)
{
    const int i = blockIdx.x * 256 + threadIdx.x;
    if (i >= E2) return;
    const int t = i / E;
    const int idx = t * N + e_dst[i];
    const int pos = offs[idx] + atomicAdd(&cur[idx], 1);
    sorted[pos] = e_src[i];
}

// ---------------- aggregation: one wave per (t,dst), bf16 gather + mean -> bf16 ----------------
__global__ __launch_bounds__(256) void agg_kernel(
    const unsigned short* __restrict__ hbf, const int* __restrict__ sorted_src,
    const int* __restrict__ offs, unsigned short* __restrict__ aggbf, int N)
{
    const int gw   = (blockIdx.x * 256 + threadIdx.x) >> 6;
    const int lane = threadIdx.x & 63;
    if (gw >= 2 * N) return;
    const int t = (gw >= N) ? 1 : 0;
    const int beg = offs[gw];
    const int end = offs[gw + 1];
    const unsigned short* hb = hbf + (size_t)t * N * D;
    float4 acc = make_float4(0.f, 0.f, 0.f, 0.f);
    for (int e = beg; e < end; ++e) {
        const int src = sorted_src[e];
        const ushort4 v = *(const ushort4*)(hb + (size_t)src * D + lane * 4);
        acc.x += bf16_to_f32(v.x); acc.y += bf16_to_f32(v.y);
        acc.z += bf16_to_f32(v.z); acc.w += bf16_to_f32(v.w);
    }
    const float inv = 1.0f / fmaxf((float)(end - beg), 1.0f);
    ushort4 o;
    o.x = bf16_rn(acc.x * inv); o.y = bf16_rn(acc.y * inv);
    o.z = bf16_rn(acc.z * inv); o.w = bf16_rn(acc.w * inv);
    *(ushort4*)(aggbf + (size_t)gw * D + lane * 4) = o;
}

// ---------------- scores (fp32 h) ----------------
__global__ __launch_bounds__(256) void score_kernel(
    const float* __restrict__ h,
    const int* __restrict__ pos_src, const int* __restrict__ pos_dst,
    const int* __restrict__ neg_src, const int* __restrict__ neg_dst,
    float* __restrict__ out, int EP, int N)
{
    const int wid  = (blockIdx.x * 256 + threadIdx.x) >> 6;
    const int lane = threadIdx.x & 63;
    if (wid >= 2 * EP) return;
    const int kind = wid / EP;
    const int k    = wid - kind * EP;
    const int s = kind ? neg_src[k] : pos_src[k];
    const int d = kind ? neg_dst[k] : pos_dst[k];
    const float4 a = *reinterpret_cast<const float4*>(h + (size_t)s * D + lane * 4);
    const float4 b = *reinterpret_cast<const float4*>(h + ((size_t)N + d) * D + lane * 4);
    float v = a.x * b.x + a.y * b.y + a.z * b.z + a.w * b.w;
    #pragma unroll
    for (int off = 32; off > 0; off >>= 1) v += __shfl_down(v, off);
    if (lane == 0) out[wid] = v;
}

extern "C" void kernel_launch(void* const* d_in, const int* in_sizes, int n_in,
                              void* d_out, int out_size, void* d_ws, size_t ws_size,
                              hipStream_t stream)
{
    const float* x      = (const float*)d_in[0];
    const float* W_in   = (const float*)d_in[1];
    const float* b_in   = (const float*)d_in[2];
    const float* lora_A = (const float*)d_in[3];
    const float* lora_B = (const float*)d_in[4];
    const float* pn_g   = (const float*)d_in[5];
    const float* pn_b   = (const float*)d_in[6];
    const float* W_self = (const float*)d_in[7];
    const float* W_neigh= (const float*)d_in[8];
    const float* b_sage = (const float*)d_in[9];
    const float* ln_g   = (const float*)d_in[10];
    const float* ln_b   = (const float*)d_in[11];
    const float* Wv     = (const float*)d_in[12];
    const float* bvp    = (const float*)d_in[13];
    const float* Wo     = (const float*)d_in[14];
    const float* bo     = (const float*)d_in[15];
    const int* e_src    = (const int*)d_in[16];
    const int* e_dst    = (const int*)d_in[17];
    const int* pos_src  = (const int*)d_in[18];
    const int* pos_dst  = (const int*)d_in[19];
    const int* neg_src  = (const int*)d_in[20];
    const int* neg_dst  = (const int*)d_in[21];

    const int N  = in_sizes[0] / (2 * D);
    const int E  = in_sizes[16] / 2;
    const int EP = in_sizes[18];
    const size_t ND2 = (size_t)2 * N * D;
    const size_t DD2 = (size_t)2 * D * D;
    const int n2 = 2 * N;

    unsigned short* P0 = (unsigned short*)d_ws;
    unsigned short* P1 = P0 + ND2;
    unsigned short* P2 = P1 + ND2;
    float* hres = (float*)(P2 + ND2);       // fp32 residual / final h
    int* cnt    = (int*)(hres + ND2);
    int* offs   = cnt  + (size_t)n2;
    int* cur    = offs + (size_t)n2 + 1;
    int* sorted = cur  + (size_t)n2;
    int* texcl  = sorted + (size_t)2 * E;
    int* bsum   = texcl + SCAN_T;
    int* bbase  = bsum + SCAN_NB;
    float* wvo  = (float*)(bbase + SCAN_NB);
    float* bvo  = wvo + DD2;
    float* b1e  = bvo + 2 * D;
    unsigned short* win_eff = (unsigned short*)(b1e + 2 * D);
    unsigned short* ws0 = win_eff + DD2;
    unsigned short* wn0 = ws0 + DD2;
    unsigned short* ws1 = wn0 + DD2;
    unsigned short* wn1 = ws1 + DD2;

    // ---- weight precompute (tiny) ----
    lora_fold_kernel<<<dim3(D, 1, 2), 256, 0, stream>>>(W_in, lora_A, lora_B, win_eff);
    f32_to_bf16_rn_kernel<<<((int)DD2 + 255) / 256, 256, 0, stream>>>(W_self,  ws0, (int)DD2);
    f32_to_bf16_rn_kernel<<<((int)DD2 + 255) / 256, 256, 0, stream>>>(W_neigh, wn0, (int)DD2);
    mm_nn_kernel<<<dim3(D, 1, 2), 256, 0, stream>>>(Wo, Wv, wvo, nullptr);
    mv_kernel<<<dim3(1, 1, 2), 256, 0, stream>>>(Wo, bvp, bo, bvo);
    mm_nn_kernel<<<dim3(D, 1, 2), 256, 0, stream>>>(wvo, W_self  + DD2, nullptr, ws1);
    mm_nn_kernel<<<dim3(D, 1, 2), 256, 0, stream>>>(wvo, W_neigh + DD2, nullptr, wn1);
    mv_kernel<<<dim3(1, 1, 2), 256, 0, stream>>>(wvo, b_sage + 2 * D, bvo, b1e);

    // ---- CSR build (edges shared by both layers) ----
    hipMemsetAsync(cnt, 0, (size_t)n2 * sizeof(int), stream);
    hipMemsetAsync(cur, 0, (size_t)n2 * sizeof(int), stream);
    count_kernel<<<(2 * E + 255) / 256, 256, 0, stream>>>(e_dst, cnt, 2 * E, N, E);
    const int sc = (n2 + SCAN_T - 1) / SCAN_T;
    scan1_kernel<<<SCAN_NB, 256, 0, stream>>>(cnt, texcl, bsum, n2, sc);
    scan2_kernel<<<1, 64, 0, stream>>>(bsum, bbase, offs, n2, SCAN_NB);
    scan3_kernel<<<SCAN_NB, 256, 0, stream>>>(cnt, texcl, bbase, offs, n2, sc);
    fill_kernel<<<(2 * E + 255) / 256, 256, 0, stream>>>(e_src, e_dst, offs, cur, sorted, 2 * E, N, E);

    const dim3 gblk(256);
    const dim3 fgrid((N + BM - 1) / BM, 1, 2);

    // ---- input projection (exact fp32 via hi/lo planes) + prenorm ----
    split_x_kernel<<<(int)((ND2 / 4 + 255) / 256), gblk, 0, stream>>>(x, P0, P1, ND2 / 4);
    gemm_ln_kernel<<<fgrid, gblk, 0, stream>>>(P0, win_eff, P1, win_eff, b_in, nullptr,
                                               pn_g, pn_b, P2, nullptr, N, 0);

    // ---- layer 0 ----
    agg_kernel<<<dim3((2 * N + 3) / 4, 1, 1), gblk, 0, stream>>>(P2, sorted, offs, P0, N);
    gemm_ln_kernel<<<fgrid, gblk, 0, stream>>>(P2, ws0, P0, wn0, b_sage, nullptr,
                                               ln_g, ln_b, P1, hres, N, 1);

    // ---- layer 1 (Wv/Wo folded; residual = hres; in-place fp32 out) ----
    agg_kernel<<<dim3((2 * N + 3) / 4, 1, 1), gblk, 0, stream>>>(P1, sorted, offs, P0, N);
    gemm_ln_kernel<<<fgrid, gblk, 0, stream>>>(P1, ws1, P0, wn1, b1e, hres,
                                               ln_g + 2 * D, ln_b + 2 * D, nullptr, hres, N, 1);

    score_kernel<<<(2 * EP + 3) / 4, gblk, 0, stream>>>(hres, pos_src, pos_dst, neg_src, neg_dst,
                                                        (float*)d_out, EP, N);
}

// Round 8
// 721.163 us; speedup vs baseline: 1.2816x; 1.2816x over previous
//
#include <hip/hip_runtime.h>

#define D 256
#define BM 128
#define BN 128
#define BK 64
#define SCAN_NB 64
#define SCAN_T (SCAN_NB * 256)

typedef __attribute__((ext_vector_type(8))) short bf16x8;
typedef __attribute__((ext_vector_type(4))) float f32x4;
typedef __attribute__((ext_vector_type(4))) unsigned int u32x4;

union frag_cvt { u32x4 u; bf16x8 h; };

__device__ __forceinline__ unsigned short bf16_rn(float f) {
    const unsigned int u = __float_as_uint(f);
    return (unsigned short)((u + 0x7FFFu + ((u >> 16) & 1u)) >> 16);
}
__device__ __forceinline__ float bf16_to_f32(unsigned short s) {
    return __uint_as_float(((unsigned int)s) << 16);
}

// ---------------- fp32 -> bf16 (RN) ----------------
__global__ void f32_to_bf16_rn_kernel(const float* __restrict__ s,
                                      unsigned short* __restrict__ d, int n)
{
    const int i = blockIdx.x * 256 + threadIdx.x;
    if (i < n) d[i] = bf16_rn(s[i]);
}

// ---------------- x -> (hi trunc, lo = exact remainder) bf16 planes ----------------
__global__ __launch_bounds__(256) void split_x_kernel(
    const float* __restrict__ x, unsigned short* __restrict__ hi,
    unsigned short* __restrict__ lo, size_t n4)
{
    const size_t i = (size_t)blockIdx.x * 256 + threadIdx.x;
    if (i >= n4) return;
    const float4 v = *(const float4*)(x + i * 4);
    ushort4 h4, l4;
    {
        const unsigned int u = __float_as_uint(v.x);
        h4.x = (unsigned short)(u >> 16);
        l4.x = (unsigned short)(__float_as_uint(v.x - __uint_as_float(u & 0xFFFF0000u)) >> 16);
    }
    {
        const unsigned int u = __float_as_uint(v.y);
        h4.y = (unsigned short)(u >> 16);
        l4.y = (unsigned short)(__float_as_uint(v.y - __uint_as_float(u & 0xFFFF0000u)) >> 16);
    }
    {
        const unsigned int u = __float_as_uint(v.z);
        h4.z = (unsigned short)(u >> 16);
        l4.z = (unsigned short)(__float_as_uint(v.z - __uint_as_float(u & 0xFFFF0000u)) >> 16);
    }
    {
        const unsigned int u = __float_as_uint(v.w);
        h4.w = (unsigned short)(u >> 16);
        l4.w = (unsigned short)(__float_as_uint(v.w - __uint_as_float(u & 0xFFFF0000u)) >> 16);
    }
    *(ushort4*)(hi + i * 4) = h4;
    *(ushort4*)(lo + i * 4) = l4;
}

// ---------------- W_eff = W + lora_B . lora_A  -> bf16 ----------------
__global__ __launch_bounds__(256) void lora_fold_kernel(
    const float* __restrict__ W, const float* __restrict__ lA,
    const float* __restrict__ lB, unsigned short* __restrict__ out)
{
    const int t = blockIdx.z, o = blockIdx.x, d = threadIdx.x;
    float acc = W[((size_t)t * D + o) * D + d];
    const float* Br = lB + ((size_t)t * D + o) * 16;
    const float* At = lA + (size_t)t * 16 * D;
    #pragma unroll
    for (int r = 0; r < 16; ++r) acc = fmaf(Br[r], At[r * D + d], acc);
    out[((size_t)t * D + o) * D + d] = bf16_rn(acc);
}

// ---------------- P[t,p,:] = sum_o X[t,p,o] * Y[t,o,:] ----------------
__global__ __launch_bounds__(256) void mm_nn_kernel(
    const float* __restrict__ X, const float* __restrict__ Y,
    float* __restrict__ Pf, unsigned short* __restrict__ Pb)
{
    const int t = blockIdx.z, p = blockIdx.x, d = threadIdx.x;
    const float* Xr = X + ((size_t)t * D + p) * D;
    const float* Yt = Y + (size_t)t * D * D;
    float acc = 0.f;
    for (int o = 0; o < D; ++o) acc = fmaf(Xr[o], Yt[(size_t)o * D + d], acc);
    if (Pf) Pf[((size_t)t * D + p) * D + d] = acc;
    if (Pb) Pb[((size_t)t * D + p) * D + d] = bf16_rn(acc);
}

// ---------------- out[t,p] = add[t,p] + sum_o M[t,p,o] * v[t,o] ----------------
__global__ __launch_bounds__(256) void mv_kernel(
    const float* __restrict__ M, const float* __restrict__ v,
    const float* __restrict__ add, float* __restrict__ out)
{
    const int t = blockIdx.z, p = threadIdx.x;
    const float* Mr = M + ((size_t)t * D + p) * D;
    const float* vr = v + (size_t)t * D;
    float acc = add[(size_t)t * D + p];
    for (int o = 0; o < D; ++o) acc = fmaf(Mr[o], vr[o], acc);
    out[(size_t)t * D + p] = acc;
}

// ---------------- staging helpers (reg-prefetch pipeline) ----------------
__device__ __forceinline__ void stage_load(const unsigned short* __restrict__ base,
                                           int r0, int kt, int tid, u32x4 reg[4])
{
    #pragma unroll
    for (int it = 0; it < 4; ++it) {
        const int g = tid + it * 256;
        const int row = g >> 3;
        const int kg = g & 7;
        reg[it] = *(const u32x4*)(base + (size_t)(r0 + row) * D + kt + kg * 8);
    }
}
__device__ __forceinline__ void stage_write(char* lds, int tid, const u32x4 reg[4])
{
    #pragma unroll
    for (int it = 0; it < 4; ++it) {
        const int g = tid + it * 256;
        const int row = g >> 3;
        const int kg = g & 7;
        const int sw = ((row * BK + kg * 8) * 2) ^ ((row & 7) << 4);
        *(u32x4*)(lds + sw) = reg[it];
    }
}

// ======== bf16 MFMA GEMM: Cbf[t] = bf16( A[t].W1[t]^T + A2[t'].W2[t]^T + bias ) ========
// Register-prefetch double-stage: next tile's global loads issue before the MFMA
// phase; vmcnt-wait lands at the next ds_write, hiding HBM latency under compute.
// NOTE: A-tail rows (m0+row >= M) are loaded unpredicated — they stay inside d_ws
// (planes are followed by more workspace) and their outputs are never stored.
__global__ __launch_bounds__(256) void gemm_bf16_kernel(
    const unsigned short* __restrict__ A, const unsigned short* __restrict__ W1,
    const unsigned short* __restrict__ A2, const unsigned short* __restrict__ W2,
    const float* __restrict__ bias,
    unsigned short* __restrict__ Cbf, int M, int swap2)
{
    const int t   = blockIdx.z;
    const int m0  = blockIdx.x * BM;
    const int n0  = blockIdx.y * BN;
    const int tid = threadIdx.x;
    const int lane = tid & 63;
    const int wid  = tid >> 6;
    const int wm = (wid >> 1) * 64;
    const int wn = (wid & 1) * 64;

    __shared__ __align__(16) unsigned short As[BM * BK];
    __shared__ __align__(16) unsigned short Bs[BN * BK];
    char* AsB = (char*)As;
    char* BsB = (char*)Bs;

    const int t2 = swap2 ? (1 - t) : t;
    const unsigned short* Aps[2] = { A  + (size_t)t  * M * D, A2 + (size_t)t2 * M * D };
    const unsigned short* Wps[2] = { W1 + (size_t)t  * D * D, W2 + (size_t)t  * D * D };

    f32x4 acc[4][4];
    #pragma unroll
    for (int i = 0; i < 4; ++i)
        #pragma unroll
        for (int j = 0; j < 4; ++j)
            acc[i][j] = (f32x4){0.f, 0.f, 0.f, 0.f};

    u32x4 areg[4], breg[4];
    stage_load(Aps[0], m0, 0, tid, areg);
    stage_load(Wps[0], n0, 0, tid, breg);

    for (int idx = 0; idx < 8; ++idx) {
        stage_write(AsB, tid, areg);
        stage_write(BsB, tid, breg);
        __syncthreads();
        if (idx < 7) {
            const int nidx = idx + 1;
            const int np  = nidx >> 2;
            const int nkt = (nidx & 3) * BK;
            stage_load(Aps[np], m0, nkt, tid, areg);
            stage_load(Wps[np], n0, nkt, tid, breg);
        }
        #pragma unroll
        for (int ks = 0; ks < 2; ++ks) {
            const int kb = ks * 64 + (lane >> 4) * 16;
            bf16x8 af[4], bfr[4];
            #pragma unroll
            for (int m = 0; m < 4; ++m) {
                const int row = wm + m * 16 + (lane & 15);
                const int sw  = (row * 128 + kb) ^ ((row & 7) << 4);
                frag_cvt c; c.u = *(u32x4*)(AsB + sw); af[m] = c.h;
            }
            #pragma unroll
            for (int n = 0; n < 4; ++n) {
                const int row = wn + n * 16 + (lane & 15);
                const int sw  = (row * 128 + kb) ^ ((row & 7) << 4);
                frag_cvt c; c.u = *(u32x4*)(BsB + sw); bfr[n] = c.h;
            }
            #pragma unroll
            for (int m = 0; m < 4; ++m)
                #pragma unroll
                for (int n = 0; n < 4; ++n)
                    acc[m][n] = __builtin_amdgcn_mfma_f32_16x16x32_bf16(af[m], bfr[n], acc[m][n], 0, 0, 0);
        }
        __syncthreads();
    }

    unsigned short* Ct = Cbf + (size_t)t * M * D;
    #pragma unroll
    for (int n = 0; n < 4; ++n) {
        const int col = n0 + wn + n * 16 + (lane & 15);
        const float bc = bias[t * D + col];
        #pragma unroll
        for (int m = 0; m < 4; ++m) {
            const int rb = m0 + wm + m * 16 + (lane >> 4) * 4;
            #pragma unroll
            for (int i = 0; i < 4; ++i) {
                const int r = rb + i;
                if (r < M) Ct[(size_t)r * D + col] = bf16_rn(acc[m][n][i] + bc);
            }
        }
    }
}

// ---------------- LayerNorm, one wave per row; bf16 in, fp32/bf16 out ----------------
__global__ __launch_bounds__(256) void ln_wave_kernel(
    const unsigned short* __restrict__ in_bf, const float* __restrict__ res,
    const float* __restrict__ g, const float* __restrict__ b,
    float* __restrict__ out_f, unsigned short* __restrict__ out_bf, int N)
{
    const int row  = (blockIdx.x * 256 + threadIdx.x) >> 6;
    const int lane = threadIdx.x & 63;
    if (row >= 2 * N) return;
    const int t = (row >= N) ? 1 : 0;
    const ushort4 iv = *(const ushort4*)(in_bf + (size_t)row * D + lane * 4);
    float4 v = make_float4(bf16_to_f32(iv.x), bf16_to_f32(iv.y),
                           bf16_to_f32(iv.z), bf16_to_f32(iv.w));
    if (res) {
        const float4 r = *(const float4*)(res + (size_t)row * D + lane * 4);
        v.x += r.x; v.y += r.y; v.z += r.z; v.w += r.w;
    }
    float s = v.x + v.y + v.z + v.w;
    #pragma unroll
    for (int off = 32; off > 0; off >>= 1) s += __shfl_xor(s, off);
    const float mu = s * (1.0f / 256.0f);
    const float4 dl = make_float4(v.x - mu, v.y - mu, v.z - mu, v.w - mu);
    float q = dl.x * dl.x + dl.y * dl.y + dl.z * dl.z + dl.w * dl.w;
    #pragma unroll
    for (int off = 32; off > 0; off >>= 1) q += __shfl_xor(q, off);
    const float rstd = rsqrtf(q * (1.0f / 256.0f) + 1e-5f);
    const float4 gv = *(const float4*)(g + (size_t)t * D + lane * 4);
    const float4 bv = *(const float4*)(b + (size_t)t * D + lane * 4);
    float4 o;
    o.x = dl.x * rstd * gv.x + bv.x;
    o.y = dl.y * rstd * gv.y + bv.y;
    o.z = dl.z * rstd * gv.z + bv.z;
    o.w = dl.w * rstd * gv.w + bv.w;
    if (out_f) *(float4*)(out_f + (size_t)row * D + lane * 4) = o;
    if (out_bf) {
        ushort4 ob;
        ob.x = bf16_rn(o.x); ob.y = bf16_rn(o.y);
        ob.z = bf16_rn(o.z); ob.w = bf16_rn(o.w);
        *(ushort4*)(out_bf + (size_t)row * D + lane * 4) = ob;
    }
}

// ---------------- CSR build ----------------
__global__ void count_kernel(const int* __restrict__ e_dst, int* __restrict__ cnt,
                             int E2, int N, int E)
{
    const int i = blockIdx.x * 256 + threadIdx.x;
    if (i >= E2) return;
    const int t = i / E;
    atomicAdd(&cnt[(size_t)t * N + e_dst[i]], 1);
}

__global__ __launch_bounds__(256) void scan1_kernel(const int* __restrict__ cnt,
                                                    int* __restrict__ texcl,
                                                    int* __restrict__ bsum, int n, int c)
{
    __shared__ int ts[256];
    const int tid = threadIdx.x;
    const int gt  = blockIdx.x * 256 + tid;
    const int b   = gt * c;
    const int e   = min(b + c, n);
    int s = 0;
    for (int i = b; i < e; ++i) s += cnt[i];
    ts[tid] = s;
    __syncthreads();
    #pragma unroll
    for (int off = 1; off < 256; off <<= 1) {
        const int v = (tid >= off) ? ts[tid - off] : 0;
        __syncthreads();
        ts[tid] += v;
        __syncthreads();
    }
    texcl[gt] = ts[tid] - s;
    if (tid == 255) bsum[blockIdx.x] = ts[255];
}

__global__ __launch_bounds__(64) void scan2_kernel(int* __restrict__ bsum,
                                                   int* __restrict__ bbase,
                                                   int* __restrict__ offs, int n, int nb)
{
    const int lane = threadIdx.x;
    int v = (lane < nb) ? bsum[lane] : 0;
    int s = v;
    #pragma unroll
    for (int off = 1; off < 64; off <<= 1) {
        const int u = __shfl_up(s, off);
        if (lane >= off) s += u;
    }
    if (lane < nb) bbase[lane] = s - v;
    if (lane == 63) offs[n] = s;
}

__global__ __launch_bounds__(256) void scan3_kernel(const int* __restrict__ cnt,
                                                    const int* __restrict__ texcl,
                                                    const int* __restrict__ bbase,
                                                    int* __restrict__ offs, int n, int c)
{
    const int tid = threadIdx.x;
    const int gt  = blockIdx.x * 256 + tid;
    const int b   = gt * c;
    const int e   = min(b + c, n);
    int base = bbase[blockIdx.x] + texcl[gt];
    for (int i = b; i < e; ++i) { offs[i] = base; base += cnt[i]; }
}

__global__ void fill_kernel(const int* __restrict__ e_src, const int* __restrict__ e_dst,
                            const int* __restrict__ offs, int* __restrict__ cur,
                            int* __restrict__ sorted, int E2, int N, int E)
{
    const int i = blockIdx.x * 256 + threadIdx.x;
    if (i >= E2) return;
    const int t = i / E;
    const int idx = t * N + e_dst[i];
    const int pos = offs[idx] + atomicAdd(&cur[idx], 1);
    sorted[pos] = e_src[i];
}

// ---------------- aggregation: one wave per (t,dst), bf16 gather + mean -> bf16 ----------------
__global__ __launch_bounds__(256) void agg_kernel(
    const unsigned short* __restrict__ hbf, const int* __restrict__ sorted_src,
    const int* __restrict__ offs, unsigned short* __restrict__ aggbf, int N)
{
    const int gw   = (blockIdx.x * 256 + threadIdx.x) >> 6;
    const int lane = threadIdx.x & 63;
    if (gw >= 2 * N) return;
    const int t = (gw >= N) ? 1 : 0;
    const int beg = offs[gw];
    const int end = offs[gw + 1];
    const unsigned short* hb = hbf + (size_t)t * N * D;
    float4 acc = make_float4(0.f, 0.f, 0.f, 0.f);
    for (int e = beg; e < end; ++e) {
        const int src = sorted_src[e];
        const ushort4 v = *(const ushort4*)(hb + (size_t)src * D + lane * 4);
        acc.x += bf16_to_f32(v.x); acc.y += bf16_to_f32(v.y);
        acc.z += bf16_to_f32(v.z); acc.w += bf16_to_f32(v.w);
    }
    const float inv = 1.0f / fmaxf((float)(end - beg), 1.0f);
    ushort4 o;
    o.x = bf16_rn(acc.x * inv); o.y = bf16_rn(acc.y * inv);
    o.z = bf16_rn(acc.z * inv); o.w = bf16_rn(acc.w * inv);
    *(ushort4*)(aggbf + (size_t)gw * D + lane * 4) = o;
}

// ---------------- scores (fp32 h) ----------------
__global__ __launch_bounds__(256) void score_kernel(
    const float* __restrict__ h,
    const int* __restrict__ pos_src, const int* __restrict__ pos_dst,
    const int* __restrict__ neg_src, const int* __restrict__ neg_dst,
    float* __restrict__ out, int EP, int N)
{
    const int wid  = (blockIdx.x * 256 + threadIdx.x) >> 6;
    const int lane = threadIdx.x & 63;
    if (wid >= 2 * EP) return;
    const int kind = wid / EP;
    const int k    = wid - kind * EP;
    const int s = kind ? neg_src[k] : pos_src[k];
    const int d = kind ? neg_dst[k] : pos_dst[k];
    const float4 a = *reinterpret_cast<const float4*>(h + (size_t)s * D + lane * 4);
    const float4 b = *reinterpret_cast<const float4*>(h + ((size_t)N + d) * D + lane * 4);
    float v = a.x * b.x + a.y * b.y + a.z * b.z + a.w * b.w;
    #pragma unroll
    for (int off = 32; off > 0; off >>= 1) v += __shfl_down(v, off);
    if (lane == 0) out[wid] = v;
}

extern "C" void kernel_launch(void* const* d_in, const int* in_sizes, int n_in,
                              void* d_out, int out_size, void* d_ws, size_t ws_size,
                              hipStream_t stream)
{
    const float* x      = (const float*)d_in[0];
    const float* W_in   = (const float*)d_in[1];
    const float* b_in   = (const float*)d_in[2];
    const float* lora_A = (const float*)d_in[3];
    const float* lora_B = (const float*)d_in[4];
    const float* pn_g   = (const float*)d_in[5];
    const float* pn_b   = (const float*)d_in[6];
    const float* W_self = (const float*)d_in[7];
    const float* W_neigh= (const float*)d_in[8];
    const float* b_sage = (const float*)d_in[9];
    const float* ln_g   = (const float*)d_in[10];
    const float* ln_b   = (const float*)d_in[11];
    const float* Wv     = (const float*)d_in[12];
    const float* bvp    = (const float*)d_in[13];
    const float* Wo     = (const float*)d_in[14];
    const float* bo     = (const float*)d_in[15];
    const int* e_src    = (const int*)d_in[16];
    const int* e_dst    = (const int*)d_in[17];
    const int* pos_src  = (const int*)d_in[18];
    const int* pos_dst  = (const int*)d_in[19];
    const int* neg_src  = (const int*)d_in[20];
    const int* neg_dst  = (const int*)d_in[21];

    const int N  = in_sizes[0] / (2 * D);
    const int E  = in_sizes[16] / 2;
    const int EP = in_sizes[18];
    const size_t ND2 = (size_t)2 * N * D;
    const size_t DD2 = (size_t)2 * D * D;
    const int n2 = 2 * N;

    unsigned short* P0 = (unsigned short*)d_ws;   // planes (bf16)
    unsigned short* P1 = P0 + ND2;
    unsigned short* P2 = P1 + ND2;
    unsigned short* T  = P2 + ND2;                // GEMM output (bf16)
    float* hres = (float*)(T + ND2);              // fp32 h (residual + score input)
    int* cnt    = (int*)(hres + ND2);
    int* offs   = cnt  + (size_t)n2;
    int* cur    = offs + (size_t)n2 + 1;
    int* sorted = cur  + (size_t)n2;
    int* texcl  = sorted + (size_t)2 * E;
    int* bsum   = texcl + SCAN_T;
    int* bbase  = bsum + SCAN_NB;
    float* wvo  = (float*)(bbase + SCAN_NB);
    float* bvo  = wvo + DD2;
    float* b1e  = bvo + 2 * D;
    unsigned short* win_eff = (unsigned short*)(b1e + 2 * D);
    unsigned short* ws0 = win_eff + DD2;
    unsigned short* wn0 = ws0 + DD2;
    unsigned short* ws1 = wn0 + DD2;
    unsigned short* wn1 = ws1 + DD2;

    // ---- weight precompute (tiny) ----
    lora_fold_kernel<<<dim3(D, 1, 2), 256, 0, stream>>>(W_in, lora_A, lora_B, win_eff);
    f32_to_bf16_rn_kernel<<<((int)DD2 + 255) / 256, 256, 0, stream>>>(W_self,  ws0, (int)DD2);
    f32_to_bf16_rn_kernel<<<((int)DD2 + 255) / 256, 256, 0, stream>>>(W_neigh, wn0, (int)DD2);
    mm_nn_kernel<<<dim3(D, 1, 2), 256, 0, stream>>>(Wo, Wv, wvo, nullptr);
    mv_kernel<<<dim3(1, 1, 2), 256, 0, stream>>>(Wo, bvp, bo, bvo);
    mm_nn_kernel<<<dim3(D, 1, 2), 256, 0, stream>>>(wvo, W_self  + DD2, nullptr, ws1);
    mm_nn_kernel<<<dim3(D, 1, 2), 256, 0, stream>>>(wvo, W_neigh + DD2, nullptr, wn1);
    mv_kernel<<<dim3(1, 1, 2), 256, 0, stream>>>(wvo, b_sage + 2 * D, bvo, b1e);

    // ---- CSR build (edges shared by both layers) ----
    hipMemsetAsync(cnt, 0, (size_t)n2 * sizeof(int), stream);
    hipMemsetAsync(cur, 0, (size_t)n2 * sizeof(int), stream);
    count_kernel<<<(2 * E + 255) / 256, 256, 0, stream>>>(e_dst, cnt, 2 * E, N, E);
    const int sc = (n2 + SCAN_T - 1) / SCAN_T;
    scan1_kernel<<<SCAN_NB, 256, 0, stream>>>(cnt, texcl, bsum, n2, sc);
    scan2_kernel<<<1, 64, 0, stream>>>(bsum, bbase, offs, n2, SCAN_NB);
    scan3_kernel<<<SCAN_NB, 256, 0, stream>>>(cnt, texcl, bbase, offs, n2, sc);
    fill_kernel<<<(2 * E + 255) / 256, 256, 0, stream>>>(e_src, e_dst, offs, cur, sorted, 2 * E, N, E);

    const dim3 gblk(256);
    const dim3 ggrid((N + BM - 1) / BM, D / BN, 2);
    const int ln_grid = (2 * N + 3) / 4;

    // ---- input projection (exact fp32 via hi/lo planes) -> T ; prenorm -> P0 bf16 ----
    split_x_kernel<<<(int)((ND2 / 4 + 255) / 256), gblk, 0, stream>>>(x, P0, P1, ND2 / 4);
    gemm_bf16_kernel<<<ggrid, gblk, 0, stream>>>(P0, win_eff, P1, win_eff, b_in, T, N, 0);
    ln_wave_kernel<<<ln_grid, gblk, 0, stream>>>(T, nullptr, pn_g, pn_b, nullptr, P0, N);

    // ---- layer 0: agg(P0)->P1 ; GEMM -> T ; LN -> hres fp32 + P2 bf16 ----
    agg_kernel<<<dim3((2 * N + 3) / 4, 1, 1), gblk, 0, stream>>>(P0, sorted, offs, P1, N);
    gemm_bf16_kernel<<<ggrid, gblk, 0, stream>>>(P0, ws0, P1, wn0, b_sage, T, N, 1);
    ln_wave_kernel<<<ln_grid, gblk, 0, stream>>>(T, nullptr, ln_g, ln_b, hres, P2, N);

    // ---- layer 1 (Wv/Wo folded): agg(P2)->P1 ; GEMM -> T ; LN(+res) -> hres ----
    agg_kernel<<<dim3((2 * N + 3) / 4, 1, 1), gblk, 0, stream>>>(P2, sorted, offs, P1, N);
    gemm_bf16_kernel<<<ggrid, gblk, 0, stream>>>(P2, ws1, P1, wn1, b1e, T, N, 1);
    ln_wave_kernel<<<ln_grid, gblk, 0, stream>>>(T, hres, ln_g + 2 * D, ln_b + 2 * D, hres, nullptr, N);

    score_kernel<<<(2 * EP + 3) / 4, gblk, 0, stream>>>(hres, pos_src, pos_dst, neg_src, neg_dst,
                                                        (float*)d_out, EP, N);
}

// Round 9
// 652.772 us; speedup vs baseline: 1.4158x; 1.1048x over previous
//
#include <hip/hip_runtime.h>

#define D 256
#define BM 128
#define BN 128
#define BK 64
#define SCAN_NB 64
#define SCAN_T (SCAN_NB * 256)

typedef __attribute__((ext_vector_type(8))) short bf16x8;
typedef __attribute__((ext_vector_type(4))) float f32x4;
typedef __attribute__((ext_vector_type(4))) unsigned int u32x4;

union frag_cvt { u32x4 u; bf16x8 h; };

__device__ __forceinline__ unsigned short bf16_rn(float f) {
    const unsigned int u = __float_as_uint(f);
    return (unsigned short)((u + 0x7FFFu + ((u >> 16) & 1u)) >> 16);
}
__device__ __forceinline__ float bf16_to_f32(unsigned short s) {
    return __uint_as_float(((unsigned int)s) << 16);
}

// ---------------- fp32 -> bf16 (RN) ----------------
__global__ void f32_to_bf16_rn_kernel(const float* __restrict__ s,
                                      unsigned short* __restrict__ d, int n)
{
    const int i = blockIdx.x * 256 + threadIdx.x;
    if (i < n) d[i] = bf16_rn(s[i]);
}

// ---------------- x -> (hi trunc, lo = exact remainder) bf16 planes ----------------
__global__ __launch_bounds__(256) void split_x_kernel(
    const float* __restrict__ x, unsigned short* __restrict__ hi,
    unsigned short* __restrict__ lo, size_t n4)
{
    const size_t i = (size_t)blockIdx.x * 256 + threadIdx.x;
    if (i >= n4) return;
    const float4 v = *(const float4*)(x + i * 4);
    ushort4 h4, l4;
    {
        const unsigned int u = __float_as_uint(v.x);
        h4.x = (unsigned short)(u >> 16);
        l4.x = (unsigned short)(__float_as_uint(v.x - __uint_as_float(u & 0xFFFF0000u)) >> 16);
    }
    {
        const unsigned int u = __float_as_uint(v.y);
        h4.y = (unsigned short)(u >> 16);
        l4.y = (unsigned short)(__float_as_uint(v.y - __uint_as_float(u & 0xFFFF0000u)) >> 16);
    }
    {
        const unsigned int u = __float_as_uint(v.z);
        h4.z = (unsigned short)(u >> 16);
        l4.z = (unsigned short)(__float_as_uint(v.z - __uint_as_float(u & 0xFFFF0000u)) >> 16);
    }
    {
        const unsigned int u = __float_as_uint(v.w);
        h4.w = (unsigned short)(u >> 16);
        l4.w = (unsigned short)(__float_as_uint(v.w - __uint_as_float(u & 0xFFFF0000u)) >> 16);
    }
    *(ushort4*)(hi + i * 4) = h4;
    *(ushort4*)(lo + i * 4) = l4;
}

// ---------------- W_eff = W + lora_B . lora_A  -> bf16 ----------------
__global__ __launch_bounds__(256) void lora_fold_kernel(
    const float* __restrict__ W, const float* __restrict__ lA,
    const float* __restrict__ lB, unsigned short* __restrict__ out)
{
    const int t = blockIdx.z, o = blockIdx.x, d = threadIdx.x;
    float acc = W[((size_t)t * D + o) * D + d];
    const float* Br = lB + ((size_t)t * D + o) * 16;
    const float* At = lA + (size_t)t * 16 * D;
    #pragma unroll
    for (int r = 0; r < 16; ++r) acc = fmaf(Br[r], At[r * D + d], acc);
    out[((size_t)t * D + o) * D + d] = bf16_rn(acc);
}

// ---------------- P[t,p,:] = sum_o X[t,p,o] * Y[t,o,:] ----------------
__global__ __launch_bounds__(256) void mm_nn_kernel(
    const float* __restrict__ X, const float* __restrict__ Y,
    float* __restrict__ Pf, unsigned short* __restrict__ Pb)
{
    const int t = blockIdx.z, p = blockIdx.x, d = threadIdx.x;
    const float* Xr = X + ((size_t)t * D + p) * D;
    const float* Yt = Y + (size_t)t * D * D;
    float acc = 0.f;
    for (int o = 0; o < D; ++o) acc = fmaf(Xr[o], Yt[(size_t)o * D + d], acc);
    if (Pf) Pf[((size_t)t * D + p) * D + d] = acc;
    if (Pb) Pb[((size_t)t * D + p) * D + d] = bf16_rn(acc);
}

// ---------------- out[t,p] = add[t,p] + sum_o M[t,p,o] * v[t,o] ----------------
__global__ __launch_bounds__(256) void mv_kernel(
    const float* __restrict__ M, const float* __restrict__ v,
    const float* __restrict__ add, float* __restrict__ out)
{
    const int t = blockIdx.z, p = threadIdx.x;
    const float* Mr = M + ((size_t)t * D + p) * D;
    const float* vr = v + (size_t)t * D;
    float acc = add[(size_t)t * D + p];
    for (int o = 0; o < D; ++o) acc = fmaf(Mr[o], vr[o], acc);
    out[(size_t)t * D + p] = acc;
}

// ---------------- A staging helpers ----------------
__device__ __forceinline__ void stage_load(const unsigned short* __restrict__ base,
                                           int r0, int kt, int tid, u32x4 reg[4])
{
    #pragma unroll
    for (int it = 0; it < 4; ++it) {
        const int g = tid + it * 256;
        const int row = g >> 3;
        const int kg = g & 7;
        reg[it] = *(const u32x4*)(base + (size_t)(r0 + row) * D + kt + kg * 8);
    }
}
__device__ __forceinline__ void stage_write(char* lds, int tid, const u32x4 reg[4])
{
    #pragma unroll
    for (int it = 0; it < 4; ++it) {
        const int g = tid + it * 256;
        const int row = g >> 3;
        const int kg = g & 7;
        const int sw = ((row * BK + kg * 8) * 2) ^ ((row & 7) << 4);
        *(u32x4*)(lds + sw) = reg[it];
    }
}

// ======== bf16 MFMA GEMM: Cbf = bf16( A.W1^T + A2[swap].W2^T + bias ) ========
// B (weights) held in registers (loaded direct from L2-resident W once per
// K-half); LDS holds only the A tile. Epilogue stages C in LDS for coalesced
// dwordx4 stores. A-tail rows load unpredicated (stay inside d_ws).
__global__ __launch_bounds__(256, 2) void gemm_bf16_kernel(
    const unsigned short* __restrict__ A, const unsigned short* __restrict__ W1,
    const unsigned short* __restrict__ A2, const unsigned short* __restrict__ W2,
    const float* __restrict__ bias,
    unsigned short* __restrict__ Cbf, int M, int swap2)
{
    const int t   = blockIdx.z;
    const int m0  = blockIdx.x * BM;
    const int n0  = blockIdx.y * BN;
    const int tid = threadIdx.x;
    const int lane = tid & 63;
    const int wid  = tid >> 6;
    const int wm = (wid >> 1) * 64;
    const int wn = (wid & 1) * 64;
    const int rgrp = lane >> 4;
    const int cidx = lane & 15;

    __shared__ __align__(16) unsigned short SH[128 * 136];   // 34.8 KB (A tile ∪ C stage)
    char* AsB = (char*)SH;

    const int t2 = swap2 ? (1 - t) : t;
    const unsigned short* Aps[2] = { A  + (size_t)t  * M * D, A2 + (size_t)t2 * M * D };
    const unsigned short* Wps[2] = { W1 + (size_t)t  * D * D, W2 + (size_t)t  * D * D };

    f32x4 acc[4][4];
    #pragma unroll
    for (int i = 0; i < 4; ++i)
        #pragma unroll
        for (int j = 0; j < 4; ++j)
            acc[i][j] = (f32x4){0.f, 0.f, 0.f, 0.f};

    bf16x8 bfr[4][4];
    u32x4 areg[4];
    stage_load(Aps[0], m0, 0, tid, areg);

    #pragma unroll
    for (int idx = 0; idx < 8; ++idx) {
        if ((idx & 1) == 0) {
            const int pass = idx >> 2;
            const int kh   = (idx >> 1) & 1;
            const unsigned short* Wp = Wps[pass];
            #pragma unroll
            for (int n = 0; n < 4; ++n) {
                const int o = n0 + wn + n * 16 + cidx;
                #pragma unroll
                for (int kk = 0; kk < 4; ++kk) {
                    frag_cvt c;
                    c.u = *(const u32x4*)(Wp + (size_t)o * D + kh * 128 + kk * 32 + rgrp * 8);
                    bfr[n][kk] = c.h;
                }
            }
        }
        stage_write(AsB, tid, areg);
        __syncthreads();
        if (idx < 7)
            stage_load(Aps[(idx + 1) >> 2], m0, ((idx + 1) & 3) * BK, tid, areg);
        #pragma unroll
        for (int ks = 0; ks < 2; ++ks) {
            const int kb = ks * 64 + rgrp * 16;
            bf16x8 af[4];
            #pragma unroll
            for (int m = 0; m < 4; ++m) {
                const int row = wm + m * 16 + cidx;
                const int sw  = (row * 128 + kb) ^ ((row & 7) << 4);
                frag_cvt c; c.u = *(u32x4*)(AsB + sw); af[m] = c.h;
            }
            #pragma unroll
            for (int m = 0; m < 4; ++m)
                #pragma unroll
                for (int n = 0; n < 4; ++n)
                    acc[m][n] = __builtin_amdgcn_mfma_f32_16x16x32_bf16(
                        af[m], bfr[n][(idx & 1) * 2 + ks], acc[m][n], 0, 0, 0);
        }
        __syncthreads();
    }

    // ---- epilogue: bias -> LDS tile (stride 136) -> coalesced stores ----
    #pragma unroll
    for (int n = 0; n < 4; ++n) {
        const int col = wn + n * 16 + cidx;
        const float bc = bias[t * D + n0 + col];
        #pragma unroll
        for (int m = 0; m < 4; ++m) {
            const int rowb = wm + m * 16 + rgrp * 4;
            #pragma unroll
            for (int i = 0; i < 4; ++i)
                SH[(rowb + i) * 136 + col] = bf16_rn(acc[m][n][i] + bc);
        }
    }
    __syncthreads();
    unsigned short* Ct = Cbf + (size_t)t * M * D;
    #pragma unroll
    for (int it = 0; it < 4; ++it) {
        const int g   = tid + it * 256;
        const int row = g >> 3;
        const int cg  = g & 7;
        const int grow = m0 + row;
        if (grow < M) {
            const u32x4 lo = *(const u32x4*)&SH[row * 136 + cg * 16];
            const u32x4 hi = *(const u32x4*)&SH[row * 136 + cg * 16 + 8];
            u32x4* dst = (u32x4*)(Ct + (size_t)grow * D + n0 + cg * 16);
            dst[0] = lo;
            dst[1] = hi;
        }
    }
}

// ---------------- LayerNorm, one wave per row; bf16 in/res/out ----------------
__global__ __launch_bounds__(256) void ln_wave_kernel(
    const unsigned short* __restrict__ in_bf, const unsigned short* __restrict__ res_bf,
    const float* __restrict__ g, const float* __restrict__ b,
    unsigned short* __restrict__ out_bf, int N)
{
    const int row  = (blockIdx.x * 256 + threadIdx.x) >> 6;
    const int lane = threadIdx.x & 63;
    if (row >= 2 * N) return;
    const int t = (row >= N) ? 1 : 0;
    const ushort4 iv = *(const ushort4*)(in_bf + (size_t)row * D + lane * 4);
    float4 v = make_float4(bf16_to_f32(iv.x), bf16_to_f32(iv.y),
                           bf16_to_f32(iv.z), bf16_to_f32(iv.w));
    if (res_bf) {
        const ushort4 rv = *(const ushort4*)(res_bf + (size_t)row * D + lane * 4);
        v.x += bf16_to_f32(rv.x); v.y += bf16_to_f32(rv.y);
        v.z += bf16_to_f32(rv.z); v.w += bf16_to_f32(rv.w);
    }
    float s = v.x + v.y + v.z + v.w;
    #pragma unroll
    for (int off = 32; off > 0; off >>= 1) s += __shfl_xor(s, off);
    const float mu = s * (1.0f / 256.0f);
    const float4 dl = make_float4(v.x - mu, v.y - mu, v.z - mu, v.w - mu);
    float q = dl.x * dl.x + dl.y * dl.y + dl.z * dl.z + dl.w * dl.w;
    #pragma unroll
    for (int off = 32; off > 0; off >>= 1) q += __shfl_xor(q, off);
    const float rstd = rsqrtf(q * (1.0f / 256.0f) + 1e-5f);
    const float4 gv = *(const float4*)(g + (size_t)t * D + lane * 4);
    const float4 bv = *(const float4*)(b + (size_t)t * D + lane * 4);
    ushort4 ob;
    ob.x = bf16_rn(dl.x * rstd * gv.x + bv.x);
    ob.y = bf16_rn(dl.y * rstd * gv.y + bv.y);
    ob.z = bf16_rn(dl.z * rstd * gv.z + bv.z);
    ob.w = bf16_rn(dl.w * rstd * gv.w + bv.w);
    *(ushort4*)(out_bf + (size_t)row * D + lane * 4) = ob;
}

// ---------------- CSR build ----------------
__global__ void count_kernel(const int* __restrict__ e_dst, int* __restrict__ cnt,
                             int E2, int N, int E)
{
    const int i = blockIdx.x * 256 + threadIdx.x;
    if (i >= E2) return;
    const int t = i / E;
    atomicAdd(&cnt[(size_t)t * N + e_dst[i]], 1);
}

__global__ __launch_bounds__(256) void scan1_kernel(const int* __restrict__ cnt,
                                                    int* __restrict__ texcl,
                                                    int* __restrict__ bsum, int n, int c)
{
    __shared__ int ts[256];
    const int tid = threadIdx.x;
    const int gt  = blockIdx.x * 256 + tid;
    const int b   = gt * c;
    const int e   = min(b + c, n);
    int s = 0;
    for (int i = b; i < e; ++i) s += cnt[i];
    ts[tid] = s;
    __syncthreads();
    #pragma unroll
    for (int off = 1; off < 256; off <<= 1) {
        const int v = (tid >= off) ? ts[tid - off] : 0;
        __syncthreads();
        ts[tid] += v;
        __syncthreads();
    }
    texcl[gt] = ts[tid] - s;
    if (tid == 255) bsum[blockIdx.x] = ts[255];
}

__global__ __launch_bounds__(64) void scan2_kernel(int* __restrict__ bsum,
                                                   int* __restrict__ bbase,
                                                   int* __restrict__ offs, int n, int nb)
{
    const int lane = threadIdx.x;
    int v = (lane < nb) ? bsum[lane] : 0;
    int s = v;
    #pragma unroll
    for (int off = 1; off < 64; off <<= 1) {
        const int u = __shfl_up(s, off);
        if (lane >= off) s += u;
    }
    if (lane < nb) bbase[lane] = s - v;
    if (lane == 63) offs[n] = s;
}

__global__ __launch_bounds__(256) void scan3_kernel(const int* __restrict__ cnt,
                                                    const int* __restrict__ texcl,
                                                    const int* __restrict__ bbase,
                                                    int* __restrict__ offs, int n, int c)
{
    const int tid = threadIdx.x;
    const int gt  = blockIdx.x * 256 + tid;
    const int b   = gt * c;
    const int e   = min(b + c, n);
    int base = bbase[blockIdx.x] + texcl[gt];
    for (int i = b; i < e; ++i) { offs[i] = base; base += cnt[i]; }
}

__global__ void fill_kernel(const int* __restrict__ e_src, const int* __restrict__ e_dst,
                            const int* __restrict__ offs, int* __restrict__ cur,
                            int* __restrict__ sorted, int E2, int N, int E)
{
    const int i = blockIdx.x * 256 + threadIdx.x;
    if (i >= E2) return;
    const int t = i / E;
    const int idx = t * N + e_dst[i];
    const int pos = offs[idx] + atomicAdd(&cur[idx], 1);
    sorted[pos] = e_src[i];
}

// ---------------- aggregation: one wave per (t,dst), bf16 gather + mean ----------------
__global__ __launch_bounds__(256) void agg_kernel(
    const unsigned short* __restrict__ hbf, const int* __restrict__ sorted_src,
    const int* __restrict__ offs, unsigned short* __restrict__ aggbf, int N)
{
    const int gw   = (blockIdx.x * 256 + threadIdx.x) >> 6;
    const int lane = threadIdx.x & 63;
    if (gw >= 2 * N) return;
    const int t = (gw >= N) ? 1 : 0;
    const int beg = offs[gw];
    const int end = offs[gw + 1];
    const unsigned short* hb = hbf + (size_t)t * N * D;
    float4 acc = make_float4(0.f, 0.f, 0.f, 0.f);
    for (int e = beg; e < end; ++e) {
        const int src = sorted_src[e];
        const ushort4 v = *(const ushort4*)(hb + (size_t)src * D + lane * 4);
        acc.x += bf16_to_f32(v.x); acc.y += bf16_to_f32(v.y);
        acc.z += bf16_to_f32(v.z); acc.w += bf16_to_f32(v.w);
    }
    const float inv = 1.0f / fmaxf((float)(end - beg), 1.0f);
    ushort4 o;
    o.x = bf16_rn(acc.x * inv); o.y = bf16_rn(acc.y * inv);
    o.z = bf16_rn(acc.z * inv); o.w = bf16_rn(acc.w * inv);
    *(ushort4*)(aggbf + (size_t)gw * D + lane * 4) = o;
}

// ---------------- scores (bf16 h, fp32 accumulate) ----------------
__global__ __launch_bounds__(256) void score_kernel(
    const unsigned short* __restrict__ h,
    const int* __restrict__ pos_src, const int* __restrict__ pos_dst,
    const int* __restrict__ neg_src, const int* __restrict__ neg_dst,
    float* __restrict__ out, int EP, int N)
{
    const int wid  = (blockIdx.x * 256 + threadIdx.x) >> 6;
    const int lane = threadIdx.x & 63;
    if (wid >= 2 * EP) return;
    const int kind = wid / EP;
    const int k    = wid - kind * EP;
    const int s = kind ? neg_src[k] : pos_src[k];
    const int d = kind ? neg_dst[k] : pos_dst[k];
    const ushort4 a = *(const ushort4*)(h + (size_t)s * D + lane * 4);
    const ushort4 b = *(const ushort4*)(h + ((size_t)N + d) * D + lane * 4);
    float v = bf16_to_f32(a.x) * bf16_to_f32(b.x)
            + bf16_to_f32(a.y) * bf16_to_f32(b.y)
            + bf16_to_f32(a.z) * bf16_to_f32(b.z)
            + bf16_to_f32(a.w) * bf16_to_f32(b.w);
    #pragma unroll
    for (int off = 32; off > 0; off >>= 1) v += __shfl_down(v, off);
    if (lane == 0) out[wid] = v;
}

extern "C" void kernel_launch(void* const* d_in, const int* in_sizes, int n_in,
                              void* d_out, int out_size, void* d_ws, size_t ws_size,
                              hipStream_t stream)
{
    const float* x      = (const float*)d_in[0];
    const float* W_in   = (const float*)d_in[1];
    const float* b_in   = (const float*)d_in[2];
    const float* lora_A = (const float*)d_in[3];
    const float* lora_B = (const float*)d_in[4];
    const float* pn_g   = (const float*)d_in[5];
    const float* pn_b   = (const float*)d_in[6];
    const float* W_self = (const float*)d_in[7];
    const float* W_neigh= (const float*)d_in[8];
    const float* b_sage = (const float*)d_in[9];
    const float* ln_g   = (const float*)d_in[10];
    const float* ln_b   = (const float*)d_in[11];
    const float* Wv     = (const float*)d_in[12];
    const float* bvp    = (const float*)d_in[13];
    const float* Wo     = (const float*)d_in[14];
    const float* bo     = (const float*)d_in[15];
    const int* e_src    = (const int*)d_in[16];
    const int* e_dst    = (const int*)d_in[17];
    const int* pos_src  = (const int*)d_in[18];
    const int* pos_dst  = (const int*)d_in[19];
    const int* neg_src  = (const int*)d_in[20];
    const int* neg_dst  = (const int*)d_in[21];

    const int N  = in_sizes[0] / (2 * D);
    const int E  = in_sizes[16] / 2;
    const int EP = in_sizes[18];
    const size_t ND2 = (size_t)2 * N * D;
    const size_t DD2 = (size_t)2 * D * D;
    const int n2 = 2 * N;

    unsigned short* P0 = (unsigned short*)d_ws;
    unsigned short* P1 = P0 + ND2;
    unsigned short* P2 = P1 + ND2;
    unsigned short* T  = P2 + ND2;
    int* cnt    = (int*)(T + ND2);
    int* offs   = cnt  + (size_t)n2;
    int* cur    = offs + (size_t)n2 + 1;
    int* sorted = cur  + (size_t)n2;
    int* texcl  = sorted + (size_t)2 * E;
    int* bsum   = texcl + SCAN_T;
    int* bbase  = bsum + SCAN_NB;
    float* wvo  = (float*)(bbase + SCAN_NB);
    float* bvo  = wvo + DD2;
    float* b1e  = bvo + 2 * D;
    unsigned short* win_eff = (unsigned short*)(b1e + 2 * D);
    unsigned short* ws0 = win_eff + DD2;
    unsigned short* wn0 = ws0 + DD2;
    unsigned short* ws1 = wn0 + DD2;
    unsigned short* wn1 = ws1 + DD2;

    // ---- weight precompute (tiny) ----
    lora_fold_kernel<<<dim3(D, 1, 2), 256, 0, stream>>>(W_in, lora_A, lora_B, win_eff);
    f32_to_bf16_rn_kernel<<<((int)DD2 + 255) / 256, 256, 0, stream>>>(W_self,  ws0, (int)DD2);
    f32_to_bf16_rn_kernel<<<((int)DD2 + 255) / 256, 256, 0, stream>>>(W_neigh, wn0, (int)DD2);
    mm_nn_kernel<<<dim3(D, 1, 2), 256, 0, stream>>>(Wo, Wv, wvo, nullptr);
    mv_kernel<<<dim3(1, 1, 2), 256, 0, stream>>>(Wo, bvp, bo, bvo);
    mm_nn_kernel<<<dim3(D, 1, 2), 256, 0, stream>>>(wvo, W_self  + DD2, nullptr, ws1);
    mm_nn_kernel<<<dim3(D, 1, 2), 256, 0, stream>>>(wvo, W_neigh + DD2, nullptr, wn1);
    mv_kernel<<<dim3(1, 1, 2), 256, 0, stream>>>(wvo, b_sage + 2 * D, bvo, b1e);

    // ---- CSR build (edges shared by both layers) ----
    hipMemsetAsync(cnt, 0, (size_t)n2 * sizeof(int), stream);
    hipMemsetAsync(cur, 0, (size_t)n2 * sizeof(int), stream);
    count_kernel<<<(2 * E + 255) / 256, 256, 0, stream>>>(e_dst, cnt, 2 * E, N, E);
    const int sc = (n2 + SCAN_T - 1) / SCAN_T;
    scan1_kernel<<<SCAN_NB, 256, 0, stream>>>(cnt, texcl, bsum, n2, sc);
    scan2_kernel<<<1, 64, 0, stream>>>(bsum, bbase, offs, n2, SCAN_NB);
    scan3_kernel<<<SCAN_NB, 256, 0, stream>>>(cnt, texcl, bbase, offs, n2, sc);
    fill_kernel<<<(2 * E + 255) / 256, 256, 0, stream>>>(e_src, e_dst, offs, cur, sorted, 2 * E, N, E);

    const dim3 gblk(256);
    const dim3 ggrid((N + BM - 1) / BM, D / BN, 2);
    const int ln_grid = (2 * N + 3) / 4;

    // ---- input projection (exact fp32 via hi/lo planes) -> T ; prenorm -> P0 ----
    split_x_kernel<<<(int)((ND2 / 4 + 255) / 256), gblk, 0, stream>>>(x, P0, P1, ND2 / 4);
    gemm_bf16_kernel<<<ggrid, gblk, 0, stream>>>(P0, win_eff, P1, win_eff, b_in, T, N, 0);
    ln_wave_kernel<<<ln_grid, gblk, 0, stream>>>(T, nullptr, pn_g, pn_b, P0, N);

    // ---- layer 0: agg(P0)->P1 ; GEMM -> T ; LN -> P2 ----
    agg_kernel<<<dim3((2 * N + 3) / 4, 1, 1), gblk, 0, stream>>>(P0, sorted, offs, P1, N);
    gemm_bf16_kernel<<<ggrid, gblk, 0, stream>>>(P0, ws0, P1, wn0, b_sage, T, N, 1);
    ln_wave_kernel<<<ln_grid, gblk, 0, stream>>>(T, nullptr, ln_g, ln_b, P2, N);

    // ---- layer 1 (Wv/Wo folded): agg(P2)->P1 ; GEMM -> T ; LN(+res=P2) -> P0 ----
    agg_kernel<<<dim3((2 * N + 3) / 4, 1, 1), gblk, 0, stream>>>(P2, sorted, offs, P1, N);
    gemm_bf16_kernel<<<ggrid, gblk, 0, stream>>>(P2, ws1, P1, wn1, b1e, T, N, 1);
    ln_wave_kernel<<<ln_grid, gblk, 0, stream>>>(T, P2, ln_g + 2 * D, ln_b + 2 * D, P0, N);

    score_kernel<<<(2 * EP + 3) / 4, gblk, 0, stream>>>(P0, pos_src, pos_dst, neg_src, neg_dst,
                                                        (float*)d_out, EP, N);
}

// Round 11
// 575.805 us; speedup vs baseline: 1.6051x; 1.1337x over previous
//
#include <hip/hip_runtime.h>

#define D 256
#define BM 128
#define BN 128
#define BK 64
#define SCAN_NB 64
#define SCAN_T (SCAN_NB * 256)

typedef __attribute__((ext_vector_type(8))) short bf16x8;
typedef __attribute__((ext_vector_type(4))) float f32x4;
typedef __attribute__((ext_vector_type(4))) unsigned int u32x4;

union frag_cvt { u32x4 u; bf16x8 h; };

__device__ __forceinline__ unsigned short bf16_rn(float f) {
    const unsigned int u = __float_as_uint(f);
    return (unsigned short)((u + 0x7FFFu + ((u >> 16) & 1u)) >> 16);
}
__device__ __forceinline__ float bf16_to_f32(unsigned short s) {
    return __uint_as_float(((unsigned int)s) << 16);
}

// ---------------- fp32 -> bf16 (RN) ----------------
__global__ void f32_to_bf16_rn_kernel(const float* __restrict__ s,
                                      unsigned short* __restrict__ d, int n)
{
    const int i = blockIdx.x * 256 + threadIdx.x;
    if (i < n) d[i] = bf16_rn(s[i]);
}

// ---------------- W_eff = W + lora_B . lora_A  -> bf16 ----------------
__global__ __launch_bounds__(256) void lora_fold_kernel(
    const float* __restrict__ W, const float* __restrict__ lA,
    const float* __restrict__ lB, unsigned short* __restrict__ out)
{
    const int t = blockIdx.z, o = blockIdx.x, d = threadIdx.x;
    float acc = W[((size_t)t * D + o) * D + d];
    const float* Br = lB + ((size_t)t * D + o) * 16;
    const float* At = lA + (size_t)t * 16 * D;
    #pragma unroll
    for (int r = 0; r < 16; ++r) acc = fmaf(Br[r], At[r * D + d], acc);
    out[((size_t)t * D + o) * D + d] = bf16_rn(acc);
}

// ---------------- P[t,p,:] = sum_o X[t,p,o] * Y[t,o,:] ----------------
__global__ __launch_bounds__(256) void mm_nn_kernel(
    const float* __restrict__ X, const float* __restrict__ Y,
    float* __restrict__ Pf, unsigned short* __restrict__ Pb)
{
    const int t = blockIdx.z, p = blockIdx.x, d = threadIdx.x;
    const float* Xr = X + ((size_t)t * D + p) * D;
    const float* Yt = Y + (size_t)t * D * D;
    float acc = 0.f;
    for (int o = 0; o < D; ++o) acc = fmaf(Xr[o], Yt[(size_t)o * D + d], acc);
    if (Pf) Pf[((size_t)t * D + p) * D + d] = acc;
    if (Pb) Pb[((size_t)t * D + p) * D + d] = bf16_rn(acc);
}

// ---------------- out[t,p] = add[t,p] + sum_o M[t,p,o] * v[t,o] ----------------
__global__ __launch_bounds__(256) void mv_kernel(
    const float* __restrict__ M, const float* __restrict__ v,
    const float* __restrict__ add, float* __restrict__ out)
{
    const int t = blockIdx.z, p = threadIdx.x;
    const float* Mr = M + ((size_t)t * D + p) * D;
    const float* vr = v + (size_t)t * D;
    float acc = add[(size_t)t * D + p];
    for (int o = 0; o < D; ++o) acc = fmaf(Mr[o], vr[o], acc);
    out[(size_t)t * D + p] = acc;
}

// ---------------- staging helpers ----------------
__device__ __forceinline__ void stage_load(const unsigned short* __restrict__ base,
                                           int r0, int kt, int tid, u32x4 reg[4])
{
    #pragma unroll
    for (int it = 0; it < 4; ++it) {
        const int g = tid + it * 256;
        const int row = g >> 3;
        const int kg = g & 7;
        reg[it] = *(const u32x4*)(base + (size_t)(r0 + row) * D + kt + kg * 8);
    }
}
__device__ __forceinline__ void stage_write(char* lds, int tid, const u32x4 reg[4])
{
    #pragma unroll
    for (int it = 0; it < 4; ++it) {
        const int g = tid + it * 256;
        const int row = g >> 3;
        const int kg = g & 7;
        const int sw = ((row * BK + kg * 8) * 2) ^ ((row & 7) << 4);
        *(u32x4*)(lds + sw) = reg[it];
    }
}
// B fragments for one 128-wide K-half, direct from global (L2-resident W)
__device__ __forceinline__ void load_bfrag(const unsigned short* __restrict__ Wp,
                                           int n0, int wn, int cidx, int rgrp,
                                           int kh, bf16x8 (&bq)[4][4])
{
    #pragma unroll
    for (int n = 0; n < 4; ++n) {
        const int o = n0 + wn + n * 16 + cidx;
        #pragma unroll
        for (int kk = 0; kk < 4; ++kk) {
            frag_cvt c;
            c.u = *(const u32x4*)(Wp + (size_t)o * D + kh * 128 + kk * 32 + rgrp * 8);
            bq[n][kk] = c.h;
        }
    }
}

// ======== layer GEMM: Cbf = bf16( A.W1^T + A2[swap].W2^T + bias ) ========
// B in registers, double-buffered one K-half ahead. A reg->LDS prefetch
// pipeline. Coalesced LDS-staged epilogue.
__global__ __launch_bounds__(256, 2) void gemm_bf16_kernel(
    const unsigned short* __restrict__ A, const unsigned short* __restrict__ W1,
    const unsigned short* __restrict__ A2, const unsigned short* __restrict__ W2,
    const float* __restrict__ bias,
    unsigned short* __restrict__ Cbf, int M, int swap2)
{
    const int t   = blockIdx.z;
    const int m0  = blockIdx.x * BM;
    const int n0  = blockIdx.y * BN;
    const int tid = threadIdx.x;
    const int lane = tid & 63;
    const int wid  = tid >> 6;
    const int wm = (wid >> 1) * 64;
    const int wn = (wid & 1) * 64;
    const int rgrp = lane >> 4;
    const int cidx = lane & 15;

    __shared__ __align__(16) unsigned short SH[128 * 136];   // A tile ∪ C stage
    char* AsB = (char*)SH;

    const int t2 = swap2 ? (1 - t) : t;
    const unsigned short* Aps[2] = { A  + (size_t)t  * M * D, A2 + (size_t)t2 * M * D };
    const unsigned short* Wps[2] = { W1 + (size_t)t  * D * D, W2 + (size_t)t  * D * D };

    f32x4 acc[4][4];
    #pragma unroll
    for (int i = 0; i < 4; ++i)
        #pragma unroll
        for (int j = 0; j < 4; ++j)
            acc[i][j] = (f32x4){0.f, 0.f, 0.f, 0.f};

    bf16x8 bq[2][4][4];
    u32x4 areg[4];
    stage_load(Aps[0], m0, 0, tid, areg);
    load_bfrag(Wps[0], n0, wn, cidx, rgrp, 0, bq[0]);

    #pragma unroll
    for (int idx = 0; idx < 8; ++idx) {
        stage_write(AsB, tid, areg);
        __syncthreads();
        if (idx < 7)
            stage_load(Aps[(idx + 1) >> 2], m0, ((idx + 1) & 3) * BK, tid, areg);
        if ((idx & 1) == 1 && idx < 7) {
            const int nh = (idx >> 1) + 1;   // next K-half 1..3 (consumed 2 tiles later)
            load_bfrag(Wps[nh >> 1], n0, wn, cidx, rgrp, nh & 1, bq[nh & 1]);
        }
        const int half = idx >> 1;
        #pragma unroll
        for (int ks = 0; ks < 2; ++ks) {
            const int kb = ks * 64 + rgrp * 16;
            bf16x8 af[4];
            #pragma unroll
            for (int m = 0; m < 4; ++m) {
                const int row = wm + m * 16 + cidx;
                const int sw  = (row * 128 + kb) ^ ((row & 7) << 4);
                frag_cvt c; c.u = *(u32x4*)(AsB + sw); af[m] = c.h;
            }
            #pragma unroll
            for (int m = 0; m < 4; ++m)
                #pragma unroll
                for (int n = 0; n < 4; ++n)
                    acc[m][n] = __builtin_amdgcn_mfma_f32_16x16x32_bf16(
                        af[m], bq[half & 1][n][(idx & 1) * 2 + ks], acc[m][n], 0, 0, 0);
        }
        __syncthreads();
    }

    // ---- epilogue: bias -> LDS (stride 136) -> coalesced stores ----
    #pragma unroll
    for (int n = 0; n < 4; ++n) {
        const int col = wn + n * 16 + cidx;
        const float bc = bias[t * D + n0 + col];
        #pragma unroll
        for (int m = 0; m < 4; ++m) {
            const int rowb = wm + m * 16 + rgrp * 4;
            #pragma unroll
            for (int i = 0; i < 4; ++i)
                SH[(rowb + i) * 136 + col] = bf16_rn(acc[m][n][i] + bc);
        }
    }
    __syncthreads();
    unsigned short* Ct = Cbf + (size_t)t * M * D;
    #pragma unroll
    for (int it = 0; it < 4; ++it) {
        const int g   = tid + it * 256;
        const int row = g >> 3;
        const int cg  = g & 7;
        const int grow = m0 + row;
        if (grow < M) {
            const u32x4 lo = *(const u32x4*)&SH[row * 136 + cg * 16];
            const u32x4 hi = *(const u32x4*)&SH[row * 136 + cg * 16 + 8];
            u32x4* dst = (u32x4*)(Ct + (size_t)grow * D + n0 + cg * 16);
            dst[0] = lo;
            dst[1] = hi;
        }
    }
}

// ======== input GEMM: Cbf = bf16( X.W^T + bias ), exact fp32 X via in-kernel hi/lo split ========
// B double-buffered: bq[0]=half0 (prologue), bq[1]=half1 loaded at kt_i==1,
// consumed from kt_i==2 — no clobber (round-10 bug fix).
__global__ __launch_bounds__(256, 2) void gemm_in_kernel(
    const float* __restrict__ X, const unsigned short* __restrict__ Wb,
    const float* __restrict__ bias, unsigned short* __restrict__ Cbf, int M)
{
    const int t   = blockIdx.z;
    const int m0  = blockIdx.x * BM;
    const int n0  = blockIdx.y * BN;
    const int tid = threadIdx.x;
    const int lane = tid & 63;
    const int wid  = tid >> 6;
    const int wm = (wid >> 1) * 64;
    const int wn = (wid & 1) * 64;
    const int rgrp = lane >> 4;
    const int cidx = lane & 15;

    __shared__ __align__(16) unsigned short SH[128 * 136];   // Ah(16K) + Al(16K) ∪ C stage
    char* AhB = (char*)SH;
    char* AlB = (char*)SH + 16384;

    const float* Xp = X + (size_t)t * M * D;
    const unsigned short* Wp = Wb + (size_t)t * D * D;

    f32x4 acc[4][4];
    #pragma unroll
    for (int i = 0; i < 4; ++i)
        #pragma unroll
        for (int j = 0; j < 4; ++j)
            acc[i][j] = (f32x4){0.f, 0.f, 0.f, 0.f};

    bf16x8 bq[2][4][4];
    float4 xr0[4], xr1[4];
    #pragma unroll
    for (int it = 0; it < 4; ++it) {
        const int g = tid + it * 256;
        const int row = g >> 3;
        const int kg = g & 7;
        const int ar = min(m0 + row, M - 1);   // clamp: X is an input buffer
        xr0[it] = *(const float4*)(Xp + (size_t)ar * D + kg * 8);
        xr1[it] = *(const float4*)(Xp + (size_t)ar * D + kg * 8 + 4);
    }
    load_bfrag(Wp, n0, wn, cidx, rgrp, 0, bq[0]);

    #pragma unroll
    for (int kt_i = 0; kt_i < 4; ++kt_i) {
        // convert fp32 -> hi (trunc) + lo (exact remainder, trunc) and stage
        #pragma unroll
        for (int it = 0; it < 4; ++it) {
            const int g = tid + it * 256;
            const int row = g >> 3;
            const int kg = g & 7;
            float v[8] = { xr0[it].x, xr0[it].y, xr0[it].z, xr0[it].w,
                           xr1[it].x, xr1[it].y, xr1[it].z, xr1[it].w };
            unsigned int hi[4], lo[4];
            #pragma unroll
            for (int j = 0; j < 4; ++j) {
                const unsigned int ua = __float_as_uint(v[2*j]);
                const unsigned int ub = __float_as_uint(v[2*j+1]);
                hi[j] = (ub & 0xFFFF0000u) | (ua >> 16);
                const float ra = v[2*j]   - __uint_as_float(ua & 0xFFFF0000u);
                const float rb = v[2*j+1] - __uint_as_float(ub & 0xFFFF0000u);
                lo[j] = (__float_as_uint(rb) & 0xFFFF0000u) | (__float_as_uint(ra) >> 16);
            }
            const int sw = ((row * BK + kg * 8) * 2) ^ ((row & 7) << 4);
            *(u32x4*)(AhB + sw) = (u32x4){hi[0], hi[1], hi[2], hi[3]};
            *(u32x4*)(AlB + sw) = (u32x4){lo[0], lo[1], lo[2], lo[3]};
        }
        __syncthreads();
        if (kt_i < 3) {
            const int kt = (kt_i + 1) * BK;
            #pragma unroll
            for (int it = 0; it < 4; ++it) {
                const int g = tid + it * 256;
                const int row = g >> 3;
                const int kg = g & 7;
                const int ar = min(m0 + row, M - 1);
                xr0[it] = *(const float4*)(Xp + (size_t)ar * D + kt + kg * 8);
                xr1[it] = *(const float4*)(Xp + (size_t)ar * D + kt + kg * 8 + 4);
            }
        }
        if (kt_i == 1) load_bfrag(Wp, n0, wn, cidx, rgrp, 1, bq[1]);  // for kt_i=2,3
        #pragma unroll
        for (int ks = 0; ks < 2; ++ks) {
            const int kb = ks * 64 + rgrp * 16;
            bf16x8 afh[4], afl[4];
            #pragma unroll
            for (int m = 0; m < 4; ++m) {
                const int row = wm + m * 16 + cidx;
                const int sw  = (row * 128 + kb) ^ ((row & 7) << 4);
                frag_cvt c1; c1.u = *(u32x4*)(AhB + sw); afh[m] = c1.h;
                frag_cvt c2; c2.u = *(u32x4*)(AlB + sw); afl[m] = c2.h;
            }
            #pragma unroll
            for (int m = 0; m < 4; ++m)
                #pragma unroll
                for (int n = 0; n < 4; ++n) {
                    const bf16x8 bfr = bq[kt_i >> 1][n][(kt_i & 1) * 2 + ks];
                    acc[m][n] = __builtin_amdgcn_mfma_f32_16x16x32_bf16(afh[m], bfr, acc[m][n], 0, 0, 0);
                    acc[m][n] = __builtin_amdgcn_mfma_f32_16x16x32_bf16(afl[m], bfr, acc[m][n], 0, 0, 0);
                }
        }
        __syncthreads();
    }

    // ---- epilogue ----
    #pragma unroll
    for (int n = 0; n < 4; ++n) {
        const int col = wn + n * 16 + cidx;
        const float bc = bias[t * D + n0 + col];
        #pragma unroll
        for (int m = 0; m < 4; ++m) {
            const int rowb = wm + m * 16 + rgrp * 4;
            #pragma unroll
            for (int i = 0; i < 4; ++i)
                SH[(rowb + i) * 136 + col] = bf16_rn(acc[m][n][i] + bc);
        }
    }
    __syncthreads();
    unsigned short* Ct = Cbf + (size_t)t * M * D;
    #pragma unroll
    for (int it = 0; it < 4; ++it) {
        const int g   = tid + it * 256;
        const int row = g >> 3;
        const int cg  = g & 7;
        const int grow = m0 + row;
        if (grow < M) {
            const u32x4 lo = *(const u32x4*)&SH[row * 136 + cg * 16];
            const u32x4 hi = *(const u32x4*)&SH[row * 136 + cg * 16 + 8];
            u32x4* dst = (u32x4*)(Ct + (size_t)grow * D + n0 + cg * 16);
            dst[0] = lo;
            dst[1] = hi;
        }
    }
}

// ---------------- LayerNorm, one wave per row; bf16 in/res/out ----------------
__global__ __launch_bounds__(256) void ln_wave_kernel(
    const unsigned short* __restrict__ in_bf, const unsigned short* __restrict__ res_bf,
    const float* __restrict__ g, const float* __restrict__ b,
    unsigned short* __restrict__ out_bf, int N)
{
    const int row  = (blockIdx.x * 256 + threadIdx.x) >> 6;
    const int lane = threadIdx.x & 63;
    if (row >= 2 * N) return;
    const int t = (row >= N) ? 1 : 0;
    const ushort4 iv = *(const ushort4*)(in_bf + (size_t)row * D + lane * 4);
    float4 v = make_float4(bf16_to_f32(iv.x), bf16_to_f32(iv.y),
                           bf16_to_f32(iv.z), bf16_to_f32(iv.w));
    if (res_bf) {
        const ushort4 rv = *(const ushort4*)(res_bf + (size_t)row * D + lane * 4);
        v.x += bf16_to_f32(rv.x); v.y += bf16_to_f32(rv.y);
        v.z += bf16_to_f32(rv.z); v.w += bf16_to_f32(rv.w);
    }
    float s = v.x + v.y + v.z + v.w;
    #pragma unroll
    for (int off = 32; off > 0; off >>= 1) s += __shfl_xor(s, off);
    const float mu = s * (1.0f / 256.0f);
    const float4 dl = make_float4(v.x - mu, v.y - mu, v.z - mu, v.w - mu);
    float q = dl.x * dl.x + dl.y * dl.y + dl.z * dl.z + dl.w * dl.w;
    #pragma unroll
    for (int off = 32; off > 0; off >>= 1) q += __shfl_xor(q, off);
    const float rstd = rsqrtf(q * (1.0f / 256.0f) + 1e-5f);
    const float4 gv = *(const float4*)(g + (size_t)t * D + lane * 4);
    const float4 bv = *(const float4*)(b + (size_t)t * D + lane * 4);
    ushort4 ob;
    ob.x = bf16_rn(dl.x * rstd * gv.x + bv.x);
    ob.y = bf16_rn(dl.y * rstd * gv.y + bv.y);
    ob.z = bf16_rn(dl.z * rstd * gv.z + bv.z);
    ob.w = bf16_rn(dl.w * rstd * gv.w + bv.w);
    *(ushort4*)(out_bf + (size_t)row * D + lane * 4) = ob;
}

// ---------------- CSR build ----------------
__global__ void count_kernel(const int* __restrict__ e_dst, int* __restrict__ cnt,
                             int E2, int N, int E)
{
    const int i = blockIdx.x * 256 + threadIdx.x;
    if (i >= E2) return;
    const int t = i / E;
    atomicAdd(&cnt[(size_t)t * N + e_dst[i]], 1);
}

__global__ __launch_bounds__(256) void scan1_kernel(const int* __restrict__ cnt,
                                                    int* __restrict__ texcl,
                                                    int* __restrict__ bsum, int n, int c)
{
    __shared__ int ts[256];
    const int tid = threadIdx.x;
    const int gt  = blockIdx.x * 256 + tid;
    const int b   = gt * c;
    const int e   = min(b + c, n);
    int s = 0;
    for (int i = b; i < e; ++i) s += cnt[i];
    ts[tid] = s;
    __syncthreads();
    #pragma unroll
    for (int off = 1; off < 256; off <<= 1) {
        const int v = (tid >= off) ? ts[tid - off] : 0;
        __syncthreads();
        ts[tid] += v;
        __syncthreads();
    }
    texcl[gt] = ts[tid] - s;
    if (tid == 255) bsum[blockIdx.x] = ts[255];
}

__global__ __launch_bounds__(64) void scan2_kernel(int* __restrict__ bsum,
                                                   int* __restrict__ bbase,
                                                   int* __restrict__ offs, int n, int nb)
{
    const int lane = threadIdx.x;
    int v = (lane < nb) ? bsum[lane] : 0;
    int s = v;
    #pragma unroll
    for (int off = 1; off < 64; off <<= 1) {
        const int u = __shfl_up(s, off);
        if (lane >= off) s += u;
    }
    if (lane < nb) bbase[lane] = s - v;
    if (lane == 63) offs[n] = s;
}

__global__ __launch_bounds__(256) void scan3_kernel(const int* __restrict__ cnt,
                                                    const int* __restrict__ texcl,
                                                    const int* __restrict__ bbase,
                                                    int* __restrict__ offs, int n, int c)
{
    const int tid = threadIdx.x;
    const int gt  = blockIdx.x * 256 + tid;
    const int b   = gt * c;
    const int e   = min(b + c, n);
    int base = bbase[blockIdx.x] + texcl[gt];
    for (int i = b; i < e; ++i) { offs[i] = base; base += cnt[i]; }
}

__global__ void fill_kernel(const int* __restrict__ e_src, const int* __restrict__ e_dst,
                            const int* __restrict__ offs, int* __restrict__ cur,
                            int* __restrict__ sorted, int E2, int N, int E)
{
    const int i = blockIdx.x * 256 + threadIdx.x;
    if (i >= E2) return;
    const int t = i / E;
    const int idx = t * N + e_dst[i];
    const int pos = offs[idx] + atomicAdd(&cur[idx], 1);
    sorted[pos] = e_src[i];
}

// ---------------- aggregation: one wave per (t,dst), bf16 gather + mean (2-way MLP) ----------------
__global__ __launch_bounds__(256) void agg_kernel(
    const unsigned short* __restrict__ hbf, const int* __restrict__ sorted_src,
    const int* __restrict__ offs, unsigned short* __restrict__ aggbf, int N)
{
    const int gw   = (blockIdx.x * 256 + threadIdx.x) >> 6;
    const int lane = threadIdx.x & 63;
    if (gw >= 2 * N) return;
    const int t = (gw >= N) ? 1 : 0;
    const int beg = offs[gw];
    const int end = offs[gw + 1];
    const unsigned short* hb = hbf + (size_t)t * N * D;
    float4 a0 = make_float4(0.f, 0.f, 0.f, 0.f);
    float4 a1 = make_float4(0.f, 0.f, 0.f, 0.f);
    int e = beg;
    for (; e + 2 <= end; e += 2) {
        const int s0 = sorted_src[e];
        const int s1 = sorted_src[e + 1];
        const ushort4 v0 = *(const ushort4*)(hb + (size_t)s0 * D + lane * 4);
        const ushort4 v1 = *(const ushort4*)(hb + (size_t)s1 * D + lane * 4);
        a0.x += bf16_to_f32(v0.x); a0.y += bf16_to_f32(v0.y);
        a0.z += bf16_to_f32(v0.z); a0.w += bf16_to_f32(v0.w);
        a1.x += bf16_to_f32(v1.x); a1.y += bf16_to_f32(v1.y);
        a1.z += bf16_to_f32(v1.z); a1.w += bf16_to_f32(v1.w);
    }
    if (e < end) {
        const int s0 = sorted_src[e];
        const ushort4 v0 = *(const ushort4*)(hb + (size_t)s0 * D + lane * 4);
        a0.x += bf16_to_f32(v0.x); a0.y += bf16_to_f32(v0.y);
        a0.z += bf16_to_f32(v0.z); a0.w += bf16_to_f32(v0.w);
    }
    const float inv = 1.0f / fmaxf((float)(end - beg), 1.0f);
    ushort4 o;
    o.x = bf16_rn((a0.x + a1.x) * inv); o.y = bf16_rn((a0.y + a1.y) * inv);
    o.z = bf16_rn((a0.z + a1.z) * inv); o.w = bf16_rn((a0.w + a1.w) * inv);
    *(ushort4*)(aggbf + (size_t)gw * D + lane * 4) = o;
}

// ---------------- scores (bf16 h, fp32 accumulate) ----------------
__global__ __launch_bounds__(256) void score_kernel(
    const unsigned short* __restrict__ h,
    const int* __restrict__ pos_src, const int* __restrict__ pos_dst,
    const int* __restrict__ neg_src, const int* __restrict__ neg_dst,
    float* __restrict__ out, int EP, int N)
{
    const int wid  = (blockIdx.x * 256 + threadIdx.x) >> 6;
    const int lane = threadIdx.x & 63;
    if (wid >= 2 * EP) return;
    const int kind = wid / EP;
    const int k    = wid - kind * EP;
    const int s = kind ? neg_src[k] : pos_src[k];
    const int d = kind ? neg_dst[k] : pos_dst[k];
    const ushort4 a = *(const ushort4*)(h + (size_t)s * D + lane * 4);
    const ushort4 b = *(const ushort4*)(h + ((size_t)N + d) * D + lane * 4);
    float v = bf16_to_f32(a.x) * bf16_to_f32(b.x)
            + bf16_to_f32(a.y) * bf16_to_f32(b.y)
            + bf16_to_f32(a.z) * bf16_to_f32(b.z)
            + bf16_to_f32(a.w) * bf16_to_f32(b.w);
    #pragma unroll
    for (int off = 32; off > 0; off >>= 1) v += __shfl_down(v, off);
    if (lane == 0) out[wid] = v;
}

extern "C" void kernel_launch(void* const* d_in, const int* in_sizes, int n_in,
                              void* d_out, int out_size, void* d_ws, size_t ws_size,
                              hipStream_t stream)
{
    const float* x      = (const float*)d_in[0];
    const float* W_in   = (const float*)d_in[1];
    const float* b_in   = (const float*)d_in[2];
    const float* lora_A = (const float*)d_in[3];
    const float* lora_B = (const float*)d_in[4];
    const float* pn_g   = (const float*)d_in[5];
    const float* pn_b   = (const float*)d_in[6];
    const float* W_self = (const float*)d_in[7];
    const float* W_neigh= (const float*)d_in[8];
    const float* b_sage = (const float*)d_in[9];
    const float* ln_g   = (const float*)d_in[10];
    const float* ln_b   = (const float*)d_in[11];
    const float* Wv     = (const float*)d_in[12];
    const float* bvp    = (const float*)d_in[13];
    const float* Wo     = (const float*)d_in[14];
    const float* bo     = (const float*)d_in[15];
    const int* e_src    = (const int*)d_in[16];
    const int* e_dst    = (const int*)d_in[17];
    const int* pos_src  = (const int*)d_in[18];
    const int* pos_dst  = (const int*)d_in[19];
    const int* neg_src  = (const int*)d_in[20];
    const int* neg_dst  = (const int*)d_in[21];

    const int N  = in_sizes[0] / (2 * D);
    const int E  = in_sizes[16] / 2;
    const int EP = in_sizes[18];
    const size_t ND2 = (size_t)2 * N * D;
    const size_t DD2 = (size_t)2 * D * D;
    const int n2 = 2 * N;

    unsigned short* P0 = (unsigned short*)d_ws;
    unsigned short* P1 = P0 + ND2;
    unsigned short* P2 = P1 + ND2;
    unsigned short* T  = P2 + ND2;
    int* cnt    = (int*)(T + ND2);
    int* offs   = cnt  + (size_t)n2;
    int* cur    = offs + (size_t)n2 + 1;
    int* sorted = cur  + (size_t)n2;
    int* texcl  = sorted + (size_t)2 * E;
    int* bsum   = texcl + SCAN_T;
    int* bbase  = bsum + SCAN_NB;
    float* wvo  = (float*)(bbase + SCAN_NB);
    float* bvo  = wvo + DD2;
    float* b1e  = bvo + 2 * D;
    unsigned short* win_eff = (unsigned short*)(b1e + 2 * D);
    unsigned short* ws0 = win_eff + DD2;
    unsigned short* wn0 = ws0 + DD2;
    unsigned short* ws1 = wn0 + DD2;
    unsigned short* wn1 = ws1 + DD2;

    // ---- weight precompute (tiny) ----
    lora_fold_kernel<<<dim3(D, 1, 2), 256, 0, stream>>>(W_in, lora_A, lora_B, win_eff);
    f32_to_bf16_rn_kernel<<<((int)DD2 + 255) / 256, 256, 0, stream>>>(W_self,  ws0, (int)DD2);
    f32_to_bf16_rn_kernel<<<((int)DD2 + 255) / 256, 256, 0, stream>>>(W_neigh, wn0, (int)DD2);
    mm_nn_kernel<<<dim3(D, 1, 2), 256, 0, stream>>>(Wo, Wv, wvo, nullptr);
    mv_kernel<<<dim3(1, 1, 2), 256, 0, stream>>>(Wo, bvp, bo, bvo);
    mm_nn_kernel<<<dim3(D, 1, 2), 256, 0, stream>>>(wvo, W_self  + DD2, nullptr, ws1);
    mm_nn_kernel<<<dim3(D, 1, 2), 256, 0, stream>>>(wvo, W_neigh + DD2, nullptr, wn1);
    mv_kernel<<<dim3(1, 1, 2), 256, 0, stream>>>(wvo, b_sage + 2 * D, bvo, b1e);

    // ---- CSR build (edges shared by both layers) ----
    hipMemsetAsync(cnt, 0, (size_t)n2 * sizeof(int), stream);
    hipMemsetAsync(cur, 0, (size_t)n2 * sizeof(int), stream);
    count_kernel<<<(2 * E + 255) / 256, 256, 0, stream>>>(e_dst, cnt, 2 * E, N, E);
    const int sc = (n2 + SCAN_T - 1) / SCAN_T;
    scan1_kernel<<<SCAN_NB, 256, 0, stream>>>(cnt, texcl, bsum, n2, sc);
    scan2_kernel<<<1, 64, 0, stream>>>(bsum, bbase, offs, n2, SCAN_NB);
    scan3_kernel<<<SCAN_NB, 256, 0, stream>>>(cnt, texcl, bbase, offs, n2, sc);
    fill_kernel<<<(2 * E + 255) / 256, 256, 0, stream>>>(e_src, e_dst, offs, cur, sorted, 2 * E, N, E);

    const dim3 gblk(256);
    const dim3 ggrid((N + BM - 1) / BM, D / BN, 2);
    const int ln_grid = (2 * N + 3) / 4;

    // ---- input projection (exact fp32 via in-kernel hi/lo split) -> T ; prenorm -> P0 ----
    gemm_in_kernel<<<ggrid, gblk, 0, stream>>>(x, win_eff, b_in, T, N);
    ln_wave_kernel<<<ln_grid, gblk, 0, stream>>>(T, nullptr, pn_g, pn_b, P0, N);

    // ---- layer 0: agg(P0)->P1 ; GEMM -> T ; LN -> P2 ----
    agg_kernel<<<dim3((2 * N + 3) / 4, 1, 1), gblk, 0, stream>>>(P0, sorted, offs, P1, N);
    gemm_bf16_kernel<<<ggrid, gblk, 0, stream>>>(P0, ws0, P1, wn0, b_sage, T, N, 1);
    ln_wave_kernel<<<ln_grid, gblk, 0, stream>>>(T, nullptr, ln_g, ln_b, P2, N);

    // ---- layer 1 (Wv/Wo folded): agg(P2)->P1 ; GEMM -> T ; LN(+res=P2) -> P0 ----
    agg_kernel<<<dim3((2 * N + 3) / 4, 1, 1), gblk, 0, stream>>>(P2, sorted, offs, P1, N);
    gemm_bf16_kernel<<<ggrid, gblk, 0, stream>>>(P2, ws1, P1, wn1, b1e, T, N, 1);
    ln_wave_kernel<<<ln_grid, gblk, 0, stream>>>(T, P2, ln_g + 2 * D, ln_b + 2 * D, P0, N);

    score_kernel<<<(2 * EP + 3) / 4, gblk, 0, stream>>>(P0, pos_src, pos_dst, neg_src, neg_dst,
                                                        (float*)d_out, EP, N);
}